// Round 1
// baseline (232.805 us; speedup 1.0000x reference)
//
#include <hip/hip_runtime.h>
#include <hip/hip_bf16.h>
#include <math.h>
#include <stdint.h>

// ---------------------------------------------------------------------------
// Attention (B=4, N=2048, D=512, H=8, Dh=64) for MI355X.
// Precision strategy: split-bf16 (hi/lo) 3-term MFMA for x@Wqkv, QK^T, AO@Wout
// (rel err ~2^-17); plain bf16 for P,V in PV (error attenuated by softmax).
// ---------------------------------------------------------------------------

typedef unsigned short u16;
typedef __attribute__((ext_vector_type(4))) float f32x4;
typedef __attribute__((ext_vector_type(8))) short bf16x8;   // 8 bf16 = 4 VGPRs

#define AS1 __attribute__((address_space(1)))
#define AS3 __attribute__((address_space(3)))
#define MFMA(a, b, c) __builtin_amdgcn_mfma_f32_16x16x32_bf16(a, b, c, 0, 0, 0)

__device__ __forceinline__ u16 f2bf(float f) {
  union { float f; unsigned u; } v; v.f = f;
  unsigned r = v.u + 0x7FFFu + ((v.u >> 16) & 1u);   // RNE
  return (u16)(r >> 16);
}
__device__ __forceinline__ float bf2f(u16 b) {
  union { float f; unsigned u; } v; v.u = ((unsigned)b) << 16; return v.f;
}
__device__ __forceinline__ void splitbf(float x, u16& hi, u16& lo) {
  hi = f2bf(x); lo = f2bf(x - bf2f(hi));
}
__device__ __forceinline__ void gld16(const u16* g, u16* l) {
  __builtin_amdgcn_global_load_lds((const AS1 void*)g, (AS3 void*)l, 16, 0, 0);
}

// ---------------- prep kernels -------------------------------------------
__global__ void k_split(const float* __restrict__ s, u16* __restrict__ h,
                        u16* __restrict__ l, int n) {
  int i = blockIdx.x * 256 + threadIdx.x;
  if (i < n) { u16 a, b; splitbf(s[i], a, b); h[i] = a; l[i] = b; }
}

// src [512][N] row-major -> dst [N][512] (transposed), split hi/lo
__global__ void k_tsplit(const float* __restrict__ s, u16* __restrict__ h,
                         u16* __restrict__ l, int N, int total) {
  int i = blockIdx.x * 256 + threadIdx.x;          // i = n*512 + k
  if (i < total) {
    int n = i >> 9, k = i & 511;
    u16 a, b; splitbf(s[(size_t)k * N + n], a, b);
    h[i] = a; l[i] = b;
  }
}

// ---------------- shared GEMM core: C[128x128] tile, K=512, BK=32 ----------
// A [M][512] hi/lo, Bt [N][512] hi/lo (both K-contiguous). 4 waves 2x2, each
// 64x64 (4x4 frags of 16x16x32). 3-term split accumulate.
__device__ __forceinline__ void gemm_core(
    const u16* __restrict__ Ah, const u16* __restrict__ Al,
    const u16* __restrict__ Bh, const u16* __restrict__ Bl,
    u16* lds, int rowA, int rowB, int tid, f32x4 (&acc)[4][4]) {
  const int wid = tid >> 6, lane = tid & 63;
  const int wr = wid >> 1, wc = wid & 1;
  const int srow = lane >> 2;          // staging row within 16-row group
  const int skel = (lane & 3) * 8;     // staging k element
  const int ar = wr * 64 + (lane & 15);
  const int br = wc * 64 + (lane & 15);
  const int kb = (lane >> 4) * 8;

  for (int kt = 0; kt < 16; ++kt) {
    const int kofs = kt * 32;
    __syncthreads();                               // prev reads done
    #pragma unroll
    for (int r = 0; r < 2; ++r) {
      const int row  = r * 64 + wid * 16 + srow;
      const int lofs = r * 2048 + wid * 512;       // ushort units
      const size_t ga = (size_t)(rowA + row) * 512 + kofs + skel;
      const size_t gb = (size_t)(rowB + row) * 512 + kofs + skel;
      gld16(Ah + ga, &lds[0 * 4096 + lofs]);
      gld16(Al + ga, &lds[1 * 4096 + lofs]);
      gld16(Bh + gb, &lds[2 * 4096 + lofs]);
      gld16(Bl + gb, &lds[3 * 4096 + lofs]);
    }
    __syncthreads();                               // vmcnt(0) drained here
    bf16x8 ah[4], al[4], bh[4], bl[4];
    #pragma unroll
    for (int i = 0; i < 4; ++i) {
      ah[i] = *(const bf16x8*)&lds[0 * 4096 + (ar + i * 16) * 32 + kb];
      al[i] = *(const bf16x8*)&lds[1 * 4096 + (ar + i * 16) * 32 + kb];
    }
    #pragma unroll
    for (int j = 0; j < 4; ++j) {
      bh[j] = *(const bf16x8*)&lds[2 * 4096 + (br + j * 16) * 32 + kb];
      bl[j] = *(const bf16x8*)&lds[3 * 4096 + (br + j * 16) * 32 + kb];
    }
    #pragma unroll
    for (int i = 0; i < 4; ++i)
      #pragma unroll
      for (int j = 0; j < 4; ++j) {
        acc[i][j] = MFMA(ah[i], bh[j], acc[i][j]);
        acc[i][j] = MFMA(ah[i], bl[j], acc[i][j]);
        acc[i][j] = MFMA(al[i], bh[j], acc[i][j]);
      }
  }
}

// ---------------- QKV projection -------------------------------------------
// qkv[m][n], n<512:Q (x0.125, split->Qh/Ql [bh][n][64]); 512..1023:K (split);
// >=1024:V -> Vt [bh][64][2048] bf16 (transposed for PV B-operand).
__global__ __launch_bounds__(256) void k_gemm_qkv(
    const u16* __restrict__ Ah, const u16* __restrict__ Al,
    const u16* __restrict__ Bh, const u16* __restrict__ Bl,
    u16* __restrict__ Qh, u16* __restrict__ Ql,
    u16* __restrict__ Kh, u16* __restrict__ Kl, u16* __restrict__ Vt) {
  __shared__ u16 lds[4 * 4096];
  const int tid = threadIdx.x, lane = tid & 63, wid = tid >> 6;
  const int wr = wid >> 1, wc = wid & 1;
  const int rowA = blockIdx.x * 128, rowB = blockIdx.y * 128;
  f32x4 acc[4][4] = {};
  gemm_core(Ah, Al, Bh, Bl, lds, rowA, rowB, tid, acc);

  #pragma unroll
  for (int i = 0; i < 4; ++i)
    #pragma unroll
    for (int j = 0; j < 4; ++j) {
      const int n = rowB + wc * 64 + j * 16 + (lane & 15);
      const int which = n >> 9;
      const int h = (n >> 6) & 7, d = n & 63;
      #pragma unroll
      for (int r = 0; r < 4; ++r) {
        const int m = rowA + wr * 64 + i * 16 + (lane >> 4) * 4 + r;
        const int b = m >> 11, iseq = m & 2047;
        float v = acc[i][j][r];
        if (which == 0) {
          u16 hi, lo; splitbf(v * 0.125f, hi, lo);
          const size_t idx = ((size_t)((b * 8 + h) * 2048 + iseq)) * 64 + d;
          Qh[idx] = hi; Ql[idx] = lo;
        } else if (which == 1) {
          u16 hi, lo; splitbf(v, hi, lo);
          const size_t idx = ((size_t)((b * 8 + h) * 2048 + iseq)) * 64 + d;
          Kh[idx] = hi; Kl[idx] = lo;
        } else {
          Vt[((size_t)((b * 8 + h) * 64 + d)) * 2048 + iseq] = f2bf(v);
        }
      }
    }
}

// ---------------- output projection ---------------------------------------
__global__ __launch_bounds__(256) void k_gemm_out(
    const u16* __restrict__ Ah, const u16* __restrict__ Al,
    const u16* __restrict__ Bh, const u16* __restrict__ Bl,
    const float* __restrict__ bias, float* __restrict__ out) {
  __shared__ u16 lds[4 * 4096];
  const int tid = threadIdx.x, lane = tid & 63, wid = tid >> 6;
  const int wr = wid >> 1, wc = wid & 1;
  const int rowA = blockIdx.x * 128, rowB = blockIdx.y * 128;
  f32x4 acc[4][4] = {};
  gemm_core(Ah, Al, Bh, Bl, lds, rowA, rowB, tid, acc);

  #pragma unroll
  for (int i = 0; i < 4; ++i)
    #pragma unroll
    for (int j = 0; j < 4; ++j) {
      const int n = rowB + wc * 64 + j * 16 + (lane & 15);
      #pragma unroll
      for (int r = 0; r < 4; ++r) {
        const int m = rowA + wr * 64 + i * 16 + (lane >> 4) * 4 + r;
        out[(size_t)m * 512 + n] = acc[i][j][r] + bias[n];
      }
    }
}

// ---------------- flash attention ------------------------------------------
// Grid (16 qblocks, 32 bh). 512 thr = 8 waves, each owns 16 Q-rows.
// KV tile 64. QK^T: 3-term split MFMA. PV: bf16 P (via per-wave LDS) x bf16 V.
// LDS tiles stored [ks][64][32] so every ds_read_b128 is bank-even.
#define LK_H 0
#define LK_L 4096
#define LV   8192
#define LP   12288

__global__ __launch_bounds__(512) void k_attn(
    const u16* __restrict__ Qh, const u16* __restrict__ Ql,
    const u16* __restrict__ Kh, const u16* __restrict__ Kl,
    const u16* __restrict__ Vt,
    u16* __restrict__ AOh, u16* __restrict__ AOl) {
  __shared__ u16 lds[20480];                      // 40 KiB
  const int tid = threadIdx.x, wid = tid >> 6, lane = tid & 63;
  const int bh = blockIdx.y;
  const size_t base = (size_t)bh * 2048 * 64;     // Q/K [bh][2048][64]; Vt [bh][64][2048]
  const int qr0 = blockIdx.x * 128 + wid * 16;

  bf16x8 qh[2], ql[2];
  {
    const size_t rq = base + (size_t)(qr0 + (lane & 15)) * 64 + (lane >> 4) * 8;
    qh[0] = *(const bf16x8*)&Qh[rq];      qh[1] = *(const bf16x8*)&Qh[rq + 32];
    ql[0] = *(const bf16x8*)&Ql[rq];      ql[1] = *(const bf16x8*)&Ql[rq + 32];
  }

  float mrun[4], srun[4];
  #pragma unroll
  for (int r = 0; r < 4; ++r) { mrun[r] = -INFINITY; srun[r] = 0.f; }
  f32x4 o[4] = {};

  const int sks = tid >> 8, srw = (tid >> 2) & 63, ssl = tid & 3;  // staging map

  for (int kv = 0; kv < 32; ++kv) {
    const int kvb = kv * 64;
    __syncthreads();
    {
      const size_t gk = base + (size_t)(kvb + srw) * 64 + sks * 32 + ssl * 8;
      const size_t gv = base + (size_t)srw * 2048 + kvb + sks * 32 + ssl * 8;
      gld16(Kh + gk, &lds[LK_H + wid * 512]);
      gld16(Kl + gk, &lds[LK_L + wid * 512]);
      gld16(Vt + gv, &lds[LV + wid * 512]);
    }
    __syncthreads();

    // ---- S = Q K^T (scaled via pre-scaled Q), 3-term split
    f32x4 s[4] = {};
    #pragma unroll
    for (int c = 0; c < 4; ++c)
      #pragma unroll
      for (int ks = 0; ks < 2; ++ks) {
        const int off = ks * 2048 + (c * 16 + (lane & 15)) * 32 + (lane >> 4) * 8;
        bf16x8 kh = *(const bf16x8*)&lds[LK_H + off];
        bf16x8 kl = *(const bf16x8*)&lds[LK_L + off];
        s[c] = MFMA(qh[ks], kh, s[c]);
        s[c] = MFMA(qh[ks], kl, s[c]);
        s[c] = MFMA(ql[ks], kh, s[c]);
      }

    // ---- online softmax (rows live in 16-lane groups)
    float pm[4];
    #pragma unroll
    for (int r = 0; r < 4; ++r)
      pm[r] = fmaxf(fmaxf(s[0][r], s[1][r]), fmaxf(s[2][r], s[3][r]));
    #pragma unroll
    for (int msk = 1; msk < 16; msk <<= 1)
      #pragma unroll
      for (int r = 0; r < 4; ++r)
        pm[r] = fmaxf(pm[r], __shfl_xor(pm[r], msk, 64));

    float mnew[4], scl[4], ps[4];
    u16 pb[4][4];
    #pragma unroll
    for (int r = 0; r < 4; ++r) {
      mnew[r] = fmaxf(mrun[r], pm[r]);
      scl[r] = __expf(mrun[r] - mnew[r]);
      ps[r] = 0.f;
    }
    #pragma unroll
    for (int c = 0; c < 4; ++c)
      #pragma unroll
      for (int r = 0; r < 4; ++r) {
        float p = __expf(s[c][r] - mnew[r]);
        u16 q_ = f2bf(p);
        pb[c][r] = q_;
        ps[r] += bf2f(q_);                 // sum the ROUNDED P -> unbiased norm
      }
    #pragma unroll
    for (int msk = 1; msk < 16; msk <<= 1)
      #pragma unroll
      for (int r = 0; r < 4; ++r)
        ps[r] += __shfl_xor(ps[r], msk, 64);
    #pragma unroll
    for (int r = 0; r < 4; ++r) {
      srun[r] = srun[r] * scl[r] + ps[r];
      mrun[r] = mnew[r];
    }
    #pragma unroll
    for (int dfr = 0; dfr < 4; ++dfr)
      #pragma unroll
      for (int r = 0; r < 4; ++r) o[dfr][r] *= scl[r];

    // ---- P -> per-wave LDS [2][16][32], then PV
    const int pbase = LP + wid * 1024;
    #pragma unroll
    for (int c = 0; c < 4; ++c)
      #pragma unroll
      for (int r = 0; r < 4; ++r)
        lds[pbase + (c >> 1) * 512 + ((lane >> 4) * 4 + r) * 32 +
            (c & 1) * 16 + (lane & 15)] = pb[c][r];
    asm volatile("s_waitcnt lgkmcnt(0)" ::: "memory");
    __builtin_amdgcn_sched_barrier(0);
    #pragma unroll
    for (int ks2 = 0; ks2 < 2; ++ks2) {
      bf16x8 pa = *(const bf16x8*)&lds[pbase + ks2 * 512 + (lane & 15) * 32 +
                                       (lane >> 4) * 8];
      #pragma unroll
      for (int dfr = 0; dfr < 4; ++dfr) {
        const int off = LV + ks2 * 2048 + (dfr * 16 + (lane & 15)) * 32 +
                        (lane >> 4) * 8;
        bf16x8 vb = *(const bf16x8*)&lds[off];
        o[dfr] = MFMA(pa, vb, o[dfr]);
      }
    }
  }

  // ---- normalize + split-write AO [8192][512]
  const int b = bh >> 3, h = bh & 7;
  #pragma unroll
  for (int r = 0; r < 4; ++r) {
    const float inv = 1.0f / srun[r];
    const int row = qr0 + (lane >> 4) * 4 + r;
    #pragma unroll
    for (int dfr = 0; dfr < 4; ++dfr) {
      const int d = dfr * 16 + (lane & 15);
      const size_t idx = ((size_t)(b * 2048 + row)) * 512 + h * 64 + d;
      u16 hi, lo; splitbf(o[dfr][r] * inv, hi, lo);
      AOh[idx] = hi; AOl[idx] = lo;
    }
  }
}

// ---------------------------------------------------------------------------
extern "C" void kernel_launch(void* const* d_in, const int* in_sizes, int n_in,
                              void* d_out, int out_size, void* d_ws, size_t ws_size,
                              hipStream_t stream) {
  const float* x    = (const float*)d_in[0];
  const float* wqkv = (const float*)d_in[1];
  const float* wout = (const float*)d_in[2];
  const float* bout = (const float*)d_in[3];
  float* out = (float*)d_out;

  char* w = (char*)d_ws;
  u16* xh  = (u16*)(w + 0);           // 8192x512 bf16 hi
  u16* xl  = (u16*)(w + 8388608);
  u16* wqh = (u16*)(w + 16777216);    // WqkvT [1536][512]
  u16* wql = (u16*)(w + 18350080);
  u16* woh = (u16*)(w + 19922944);    // WoutT [512][512]
  u16* wol = (u16*)(w + 20447232);
  u16* Qh  = (u16*)(w + 20971520);    // [32][2048][64]
  u16* Ql  = (u16*)(w + 29360128);
  u16* Kh  = (u16*)(w + 37748736);
  u16* Kl  = (u16*)(w + 46137344);
  u16* Vt  = (u16*)(w + 54525952);    // [32][64][2048]
  u16* AOh = (u16*)(w + 62914560);    // [8192][512]
  u16* AOl = (u16*)(w + 71303168);    // total 79691776 bytes

  k_split <<<4194304 / 256, 256, 0, stream>>>(x, xh, xl, 4194304);
  k_tsplit<<< 786432 / 256, 256, 0, stream>>>(wqkv, wqh, wql, 1536, 786432);
  k_tsplit<<< 262144 / 256, 256, 0, stream>>>(wout, woh, wol, 512, 262144);
  k_gemm_qkv<<<dim3(64, 12), 256, 0, stream>>>(xh, xl, wqh, wql,
                                               Qh, Ql, Kh, Kl, Vt);
  k_attn<<<dim3(16, 32), 512, 0, stream>>>(Qh, Ql, Kh, Kl, Vt, AOh, AOl);
  k_gemm_out<<<dim3(64, 4), 256, 0, stream>>>(AOh, AOl, woh, wol, bout, out);
}

// Round 2
// 191.075 us; speedup vs baseline: 1.2184x; 1.2184x over previous
//
#include <hip/hip_runtime.h>
#include <hip/hip_bf16.h>
#include <math.h>
#include <stdint.h>

// ---------------------------------------------------------------------------
// Attention (B=4, N=2048, D=512, H=8, Dh=64) for MI355X.
// Precision: split-bf16 (hi/lo) 3-term MFMA for x@Wqkv, QK^T, AO@Wout;
// plain bf16 P,V in PV (softmax-attenuated error).
// R2: LDS XOR-swizzle (T2, involution byte^=((byte>>7)&7)<<4, pre-swizzled
// global sources for global_load_lds) + double-buffered KV prefetch with
// counted vmcnt(3) + raw s_barrier (T3-lite) in k_attn.
// ---------------------------------------------------------------------------

typedef unsigned short u16;
typedef __attribute__((ext_vector_type(4))) float f32x4;
typedef __attribute__((ext_vector_type(8))) short bf16x8;   // 8 bf16 = 4 VGPRs
typedef __attribute__((ext_vector_type(4))) short s16x4;

#define AS1 __attribute__((address_space(1)))
#define AS3 __attribute__((address_space(3)))
#define MFMA(a, b, c) __builtin_amdgcn_mfma_f32_16x16x32_bf16(a, b, c, 0, 0, 0)

__device__ __forceinline__ u16 f2bf(float f) {
  union { float f; unsigned u; } v; v.f = f;
  unsigned r = v.u + 0x7FFFu + ((v.u >> 16) & 1u);   // RNE
  return (u16)(r >> 16);
}
__device__ __forceinline__ float bf2f(u16 b) {
  union { float f; unsigned u; } v; v.u = ((unsigned)b) << 16; return v.f;
}
__device__ __forceinline__ void splitbf(float x, u16& hi, u16& lo) {
  hi = f2bf(x); lo = f2bf(x - bf2f(hi));
}
__device__ __forceinline__ void gld16(const u16* g, u16* l) {
  __builtin_amdgcn_global_load_lds((const AS1 void*)g, (AS3 void*)l, 16, 0, 0);
}

// ---------------- prep kernels -------------------------------------------
__global__ void k_split(const float* __restrict__ s, u16* __restrict__ h,
                        u16* __restrict__ l, int n) {
  int i = blockIdx.x * 256 + threadIdx.x;
  if (i < n) { u16 a, b; splitbf(s[i], a, b); h[i] = a; l[i] = b; }
}

// src [512][N] row-major -> dst [N][512] (transposed), split hi/lo
__global__ void k_tsplit(const float* __restrict__ s, u16* __restrict__ h,
                         u16* __restrict__ l, int N, int total) {
  int i = blockIdx.x * 256 + threadIdx.x;          // i = n*512 + k
  if (i < total) {
    int n = i >> 9, k = i & 511;
    u16 a, b; splitbf(s[(size_t)k * N + n], a, b);
    h[i] = a; l[i] = b;
  }
}

// ---------------- shared GEMM core: C[128x128] tile, K=512, BK=32 ----------
// A [M][512] hi/lo, Bt [N][512] hi/lo. 4 waves 2x2, each 64x64.
// LDS: 4 x 8KB tiles (Ah, Al, Bh, Bl), 64B rows, XOR-swizzled.
__device__ __forceinline__ void gemm_core(
    const u16* __restrict__ Ah, const u16* __restrict__ Al,
    const u16* __restrict__ Bh, const u16* __restrict__ Bl,
    char* sm, int rowA, int rowB, int tid, f32x4 (&acc)[4][4]) {
  const int wid = tid >> 6, lane = tid & 63;
  const int x = lane & 15, h = lane >> 4;
  const int wr = wid >> 1, wc = wid & 1;
  // staging: dest byte (tile-rel) = r*4096 + wid*1024 + lane*16; logical via swz
  const int d0 = wid * 1024 + lane * 16;
  const int lg0 = d0 ^ (((d0 >> 7) & 7) << 4);
  const int srow = lg0 >> 6;              // 0..63 (+r*64)
  const int scol = (lg0 & 63) >> 1;       // u16 col within 32-wide row
  const int swk = ((lane >> 1) & 7) << 4; // read-side xor term (row bits 1-3 = x>>1)
  const int ar = wr * 64 + x, br = wc * 64 + x;

  for (int kt = 0; kt < 16; ++kt) {
    const int kofs = kt * 32;
    __syncthreads();
    #pragma unroll
    for (int r = 0; r < 2; ++r) {
      const int row  = r * 64 + srow;
      const int ldst = r * 4096 + wid * 1024;
      const size_t ga = (size_t)(rowA + row) * 512 + kofs + scol;
      const size_t gb = (size_t)(rowB + row) * 512 + kofs + scol;
      gld16(Ah + ga, (u16*)(sm + ldst));
      gld16(Al + ga, (u16*)(sm + 8192 + ldst));
      gld16(Bh + gb, (u16*)(sm + 16384 + ldst));
      gld16(Bl + gb, (u16*)(sm + 24576 + ldst));
    }
    __syncthreads();
    bf16x8 a_h[4], a_l[4], b_h[4], b_l[4];
    #pragma unroll
    for (int i = 0; i < 4; ++i) {
      const int off = ((ar + i * 16) * 64 + h * 16) ^ swk;
      a_h[i] = *(const bf16x8*)(sm + off);
      a_l[i] = *(const bf16x8*)(sm + 8192 + off);
    }
    #pragma unroll
    for (int j = 0; j < 4; ++j) {
      const int off = ((br + j * 16) * 64 + h * 16) ^ swk;
      b_h[j] = *(const bf16x8*)(sm + 16384 + off);
      b_l[j] = *(const bf16x8*)(sm + 24576 + off);
    }
    #pragma unroll
    for (int i = 0; i < 4; ++i)
      #pragma unroll
      for (int j = 0; j < 4; ++j) {
        acc[i][j] = MFMA(a_h[i], b_h[j], acc[i][j]);
        acc[i][j] = MFMA(a_h[i], b_l[j], acc[i][j]);
        acc[i][j] = MFMA(a_l[i], b_h[j], acc[i][j]);
      }
  }
}

// ---------------- QKV projection -------------------------------------------
__global__ __launch_bounds__(256) void k_gemm_qkv(
    const u16* __restrict__ Ah, const u16* __restrict__ Al,
    const u16* __restrict__ Bh, const u16* __restrict__ Bl,
    u16* __restrict__ Qh, u16* __restrict__ Ql,
    u16* __restrict__ Kh, u16* __restrict__ Kl, u16* __restrict__ Vt) {
  __shared__ __align__(1024) char sm[32768];
  const int tid = threadIdx.x, lane = tid & 63, wid = tid >> 6;
  const int x = lane & 15, h = lane >> 4;
  const int wr = wid >> 1, wc = wid & 1;
  const int rowA = blockIdx.x * 128, rowB = blockIdx.y * 128;
  f32x4 acc[4][4] = {};
  gemm_core(Ah, Al, Bh, Bl, sm, rowA, rowB, tid, acc);

  #pragma unroll
  for (int i = 0; i < 4; ++i)
    #pragma unroll
    for (int j = 0; j < 4; ++j) {
      const int n = rowB + wc * 64 + j * 16 + x;
      const int which = n >> 9;
      const int hh = (n >> 6) & 7, d = n & 63;
      const int m0 = rowA + wr * 64 + i * 16 + h * 4;
      const int b = m0 >> 11, is0 = m0 & 2047;
      if (which == 0) {
        #pragma unroll
        for (int r = 0; r < 4; ++r) {
          u16 hi, lo; splitbf(acc[i][j][r] * 0.125f, hi, lo);
          const size_t idx = ((size_t)((b * 8 + hh) * 2048 + is0 + r)) * 64 + d;
          Qh[idx] = hi; Ql[idx] = lo;
        }
      } else if (which == 1) {
        #pragma unroll
        for (int r = 0; r < 4; ++r) {
          u16 hi, lo; splitbf(acc[i][j][r], hi, lo);
          const size_t idx = ((size_t)((b * 8 + hh) * 2048 + is0 + r)) * 64 + d;
          Kh[idx] = hi; Kl[idx] = lo;
        }
      } else {
        s16x4 vv;
        #pragma unroll
        for (int r = 0; r < 4; ++r) vv[r] = (short)f2bf(acc[i][j][r]);
        *(s16x4*)&Vt[((size_t)((b * 8 + hh) * 64 + d)) * 2048 + is0] = vv;
      }
    }
}

// ---------------- output projection ---------------------------------------
__global__ __launch_bounds__(256) void k_gemm_out(
    const u16* __restrict__ Ah, const u16* __restrict__ Al,
    const u16* __restrict__ Bh, const u16* __restrict__ Bl,
    const float* __restrict__ bias, float* __restrict__ out) {
  __shared__ __align__(1024) char sm[32768];
  const int tid = threadIdx.x, lane = tid & 63, wid = tid >> 6;
  const int x = lane & 15, h = lane >> 4;
  const int wr = wid >> 1, wc = wid & 1;
  const int rowA = blockIdx.x * 128, rowB = blockIdx.y * 128;
  f32x4 acc[4][4] = {};
  gemm_core(Ah, Al, Bh, Bl, sm, rowA, rowB, tid, acc);

  #pragma unroll
  for (int i = 0; i < 4; ++i)
    #pragma unroll
    for (int j = 0; j < 4; ++j) {
      const int n = rowB + wc * 64 + j * 16 + x;
      #pragma unroll
      for (int r = 0; r < 4; ++r) {
        const int m = rowA + wr * 64 + i * 16 + h * 4 + r;
        out[(size_t)m * 512 + n] = acc[i][j][r] + bias[n];
      }
    }
}

// ---------------- flash attention ------------------------------------------
// Grid (16 qblocks, 32 bh), 512 thr = 8 waves x 16 Q-rows. KV tile 64.
// Double-buffered K/V (swizzled) with counted vmcnt(3); P per-wave swizzled.
// LDS: buf0 {KH 0, KL 8K, V 16K}, buf1 {24K, 32K, 40K}, P 48K..64K.
#define PBASE 49152

__global__ __launch_bounds__(512) void k_attn(
    const u16* __restrict__ Qh, const u16* __restrict__ Ql,
    const u16* __restrict__ Kh, const u16* __restrict__ Kl,
    const u16* __restrict__ Vt,
    u16* __restrict__ AOh, u16* __restrict__ AOl) {
  __shared__ __align__(1024) char sm[65536];
  const int tid = threadIdx.x, wid = tid >> 6, lane = tid & 63;
  const int x = lane & 15, h = lane >> 4;
  const int bh = blockIdx.y;
  const size_t base = (size_t)bh * 2048 * 64;   // Q/K [bh][2048][64]; Vt [bh][64][2048]
  const int qr0 = blockIdx.x * 128 + wid * 16;

  bf16x8 qh[2], ql[2];
  {
    const size_t rq = base + (size_t)(qr0 + x) * 64 + h * 8;
    qh[0] = *(const bf16x8*)&Qh[rq];      qh[1] = *(const bf16x8*)&Qh[rq + 32];
    ql[0] = *(const bf16x8*)&Ql[rq];      ql[1] = *(const bf16x8*)&Ql[rq + 32];
  }

  // staging: dest (region-rel) = wid*1024 + lane*16; logical via involution
  const int dest = wid * 1024 + lane * 16;
  const int lg = dest ^ (((dest >> 7) & 7) << 4);
  const int sks = lg >> 12, srw = (lg >> 6) & 63, sco = (lg >> 1) & 31;
  const size_t offK = (size_t)srw * 64 + sks * 32 + sco;    // + kvb*64
  const size_t offV = (size_t)srw * 2048 + sks * 32 + sco;  // + kvb

  const int swk = ((lane >> 1) & 7) << 4;   // read xor for 64B-row tiles
  const int swp = (x & 7) << 4;             // read xor for P (128B rows)
  const int pwav = PBASE + wid * 2048;

  float mrun[4], srun[4];
  #pragma unroll
  for (int r = 0; r < 4; ++r) { mrun[r] = -INFINITY; srun[r] = 0.f; }
  f32x4 o[4] = {};

  {  // stage tile 0 -> buf0
    char* lb = sm + wid * 1024;
    gld16(Kh + base + offK, (u16*)lb);
    gld16(Kl + base + offK, (u16*)(lb + 8192));
    gld16(Vt + base + offV, (u16*)(lb + 16384));
  }

  for (int kv = 0; kv < 32; ++kv) {
    const int bb = (kv & 1) * 24576;
    __builtin_amdgcn_s_barrier();                 // prev compute done -> alt buf free
    if (kv < 31) {
      const size_t kvb = (size_t)(kv + 1) * 64;
      char* lb = sm + (24576 - bb) + wid * 1024;
      gld16(Kh + base + kvb * 64 + offK, (u16*)lb);
      gld16(Kl + base + kvb * 64 + offK, (u16*)(lb + 8192));
      gld16(Vt + base + kvb + offV, (u16*)(lb + 16384));
      asm volatile("s_waitcnt vmcnt(3)" ::: "memory");  // my tile-kv loads done
    } else {
      asm volatile("s_waitcnt vmcnt(0)" ::: "memory");
    }
    __builtin_amdgcn_s_barrier();                 // everyone's tile-kv landed

    // ---- S = Q K^T (Q pre-scaled), 3-term split
    f32x4 s4[4] = {};
    #pragma unroll
    for (int c = 0; c < 4; ++c)
      #pragma unroll
      for (int ks = 0; ks < 2; ++ks) {
        const int off = (bb + ks * 4096 + (c * 16 + x) * 64 + h * 16) ^ swk;
        bf16x8 kh_ = *(const bf16x8*)(sm + off);
        bf16x8 kl_ = *(const bf16x8*)(sm + off + 8192);
        s4[c] = MFMA(qh[ks], kh_, s4[c]);
        s4[c] = MFMA(qh[ks], kl_, s4[c]);
        s4[c] = MFMA(ql[ks], kh_, s4[c]);
      }

    // ---- online softmax (rows q = h*4+r, cols distributed over x-lanes)
    float pm[4];
    #pragma unroll
    for (int r = 0; r < 4; ++r)
      pm[r] = fmaxf(fmaxf(s4[0][r], s4[1][r]), fmaxf(s4[2][r], s4[3][r]));
    #pragma unroll
    for (int msk = 1; msk < 16; msk <<= 1)
      #pragma unroll
      for (int r = 0; r < 4; ++r)
        pm[r] = fmaxf(pm[r], __shfl_xor(pm[r], msk, 64));

    float mnew[4], scl[4], psl[4];
    u16 pb[4][4];
    #pragma unroll
    for (int r = 0; r < 4; ++r) {
      mnew[r] = fmaxf(mrun[r], pm[r]);
      scl[r] = __expf(mrun[r] - mnew[r]);
      psl[r] = 0.f;
    }
    #pragma unroll
    for (int c = 0; c < 4; ++c)
      #pragma unroll
      for (int r = 0; r < 4; ++r) {
        float p = __expf(s4[c][r] - mnew[r]);
        u16 q_ = f2bf(p);
        pb[c][r] = q_;
        psl[r] += bf2f(q_);          // partial sum (x-slice); reduced at end
      }
    #pragma unroll
    for (int r = 0; r < 4; ++r) {
      srun[r] = srun[r] * scl[r] + psl[r];
      mrun[r] = mnew[r];
    }
    #pragma unroll
    for (int dfr = 0; dfr < 4; ++dfr)
      #pragma unroll
      for (int r = 0; r < 4; ++r) o[dfr][r] *= scl[r];

    // ---- P -> per-wave LDS [16 q][64 k] (swizzled), then PV
    #pragma unroll
    for (int c = 0; c < 4; ++c)
      #pragma unroll
      for (int r = 0; r < 4; ++r) {
        const int off = (pwav + (h * 4 + r) * 128 + c * 32 + x * 2)
                        ^ ((((h & 1) * 4 + r)) << 4);
        *(u16*)(sm + off) = pb[c][r];
      }
    asm volatile("s_waitcnt lgkmcnt(0)" ::: "memory");
    __builtin_amdgcn_sched_barrier(0);
    #pragma unroll
    for (int ks2 = 0; ks2 < 2; ++ks2) {
      const int offp = (pwav + x * 128 + ks2 * 64 + h * 16) ^ swp;
      bf16x8 pa = *(const bf16x8*)(sm + offp);
      #pragma unroll
      for (int dfr = 0; dfr < 4; ++dfr) {
        const int offv = (bb + 16384 + ks2 * 4096 + (dfr * 16 + x) * 64 + h * 16)
                         ^ swk;
        bf16x8 vb = *(const bf16x8*)(sm + offv);
        o[dfr] = MFMA(pa, vb, o[dfr]);
      }
    }
  }

  // ---- final x-lane sum reduce, normalize, split-write AO [8192][512]
  #pragma unroll
  for (int msk = 1; msk < 16; msk <<= 1)
    #pragma unroll
    for (int r = 0; r < 4; ++r)
      srun[r] += __shfl_xor(srun[r], msk, 64);

  const int b = bh >> 3, hd = bh & 7;
  #pragma unroll
  for (int r = 0; r < 4; ++r) {
    const float inv = 1.0f / srun[r];
    const int row = qr0 + h * 4 + r;
    #pragma unroll
    for (int dfr = 0; dfr < 4; ++dfr) {
      const int d = dfr * 16 + x;
      const size_t idx = ((size_t)(b * 2048 + row)) * 512 + hd * 64 + d;
      u16 hi, lo; splitbf(o[dfr][r] * inv, hi, lo);
      AOh[idx] = hi; AOl[idx] = lo;
    }
  }
}

// ---------------------------------------------------------------------------
extern "C" void kernel_launch(void* const* d_in, const int* in_sizes, int n_in,
                              void* d_out, int out_size, void* d_ws, size_t ws_size,
                              hipStream_t stream) {
  const float* x    = (const float*)d_in[0];
  const float* wqkv = (const float*)d_in[1];
  const float* wout = (const float*)d_in[2];
  const float* bout = (const float*)d_in[3];
  float* out = (float*)d_out;

  char* w = (char*)d_ws;
  u16* xh  = (u16*)(w + 0);           // 8192x512 bf16 hi
  u16* xl  = (u16*)(w + 8388608);
  u16* wqh = (u16*)(w + 16777216);    // WqkvT [1536][512]
  u16* wql = (u16*)(w + 18350080);
  u16* woh = (u16*)(w + 19922944);    // WoutT [512][512]
  u16* wol = (u16*)(w + 20447232);
  u16* Qh  = (u16*)(w + 20971520);    // [32][2048][64]
  u16* Ql  = (u16*)(w + 29360128);
  u16* Kh  = (u16*)(w + 37748736);
  u16* Kl  = (u16*)(w + 46137344);
  u16* Vt  = (u16*)(w + 54525952);    // [32][64][2048]
  u16* AOh = (u16*)(w + 62914560);    // [8192][512]
  u16* AOl = (u16*)(w + 71303168);    // total 79691776 bytes

  k_split <<<4194304 / 256, 256, 0, stream>>>(x, xh, xl, 4194304);
  k_tsplit<<< 786432 / 256, 256, 0, stream>>>(wqkv, wqh, wql, 1536, 786432);
  k_tsplit<<< 262144 / 256, 256, 0, stream>>>(wout, woh, wol, 512, 262144);
  k_gemm_qkv<<<dim3(64, 12), 256, 0, stream>>>(xh, xl, wqh, wql,
                                               Qh, Ql, Kh, Kl, Vt);
  k_attn<<<dim3(16, 32), 512, 0, stream>>>(Qh, Ql, Kh, Kl, Vt, AOh, AOl);
  k_gemm_out<<<dim3(64, 4), 256, 0, stream>>>(AOh, AOl, woh, wol, bout, out);
}

// Round 3
// 175.280 us; speedup vs baseline: 1.3282x; 1.0901x over previous
//
#include <hip/hip_runtime.h>
#include <hip/hip_bf16.h>
#include <math.h>
#include <stdint.h>

// ---------------------------------------------------------------------------
// Attention (B=4, N=2048, D=512, H=8, Dh=64) for MI355X.
// Precision: split-bf16 (hi/lo) 3-term MFMA for x@Wqkv, QK^T, AO@Wout;
// plain bf16 P,V in PV (softmax-attenuated error).
// R3: swapped QK^T (S rows lane-local) + cvt_pk_bf16 + ds_bpermute P
// redistribution + defer-rescale (THR=7, log2 domain) + exp2-direct +
// XCD-aware block swizzle. LDS 48KB (P buffer eliminated).
// ---------------------------------------------------------------------------

typedef unsigned short u16;
typedef __attribute__((ext_vector_type(4))) float f32x4;
typedef __attribute__((ext_vector_type(8))) short bf16x8;   // 8 bf16 = 4 VGPRs
typedef __attribute__((ext_vector_type(4))) short s16x4;

#define AS1 __attribute__((address_space(1)))
#define AS3 __attribute__((address_space(3)))
#define MFMA(a, b, c) __builtin_amdgcn_mfma_f32_16x16x32_bf16(a, b, c, 0, 0, 0)
#define QSCALE 0.180336880f   /* 0.125 * log2(e): logits in log2 domain */

__device__ __forceinline__ u16 f2bf(float f) {
  union { float f; unsigned u; } v; v.f = f;
  unsigned r = v.u + 0x7FFFu + ((v.u >> 16) & 1u);   // RNE
  return (u16)(r >> 16);
}
__device__ __forceinline__ float bf2f(u16 b) {
  union { float f; unsigned u; } v; v.u = ((unsigned)b) << 16; return v.f;
}
__device__ __forceinline__ void splitbf(float x, u16& hi, u16& lo) {
  hi = f2bf(x); lo = f2bf(x - bf2f(hi));
}
__device__ __forceinline__ void gld16(const u16* g, u16* l) {
  __builtin_amdgcn_global_load_lds((const AS1 void*)g, (AS3 void*)l, 16, 0, 0);
}
__device__ __forceinline__ float u2f(unsigned u) {
  union { unsigned u; float f; } v; v.u = u; return v.f;
}
__device__ __forceinline__ unsigned f2u(float f) {
  union { float f; unsigned u; } v; v.f = f; return v.u;
}
__device__ __forceinline__ int cvtpk(float lo, float hi) {
  int r; asm("v_cvt_pk_bf16_f32 %0, %1, %2" : "=v"(r) : "v"(lo), "v"(hi));
  return r;
}
__device__ __forceinline__ float fexp2(float x) {
  float r; asm("v_exp_f32 %0, %1" : "=v"(r) : "v"(x));
  return r;
}

// ---------------- prep kernels -------------------------------------------
__global__ void k_split(const float* __restrict__ s, u16* __restrict__ h,
                        u16* __restrict__ l, int n) {
  int i = blockIdx.x * 256 + threadIdx.x;
  if (i < n) { u16 a, b; splitbf(s[i], a, b); h[i] = a; l[i] = b; }
}

// src [512][N] row-major -> dst [N][512] (transposed), split hi/lo
__global__ void k_tsplit(const float* __restrict__ s, u16* __restrict__ h,
                         u16* __restrict__ l, int N, int total) {
  int i = blockIdx.x * 256 + threadIdx.x;          // i = n*512 + k
  if (i < total) {
    int n = i >> 9, k = i & 511;
    u16 a, b; splitbf(s[(size_t)k * N + n], a, b);
    h[i] = a; l[i] = b;
  }
}

// ---------------- shared GEMM core: C[128x128] tile, K=512, BK=32 ----------
__device__ __forceinline__ void gemm_core(
    const u16* __restrict__ Ah, const u16* __restrict__ Al,
    const u16* __restrict__ Bh, const u16* __restrict__ Bl,
    char* sm, int rowA, int rowB, int tid, f32x4 (&acc)[4][4]) {
  const int wid = tid >> 6, lane = tid & 63;
  const int x = lane & 15, h = lane >> 4;
  const int wr = wid >> 1, wc = wid & 1;
  const int d0 = wid * 1024 + lane * 16;
  const int lg0 = d0 ^ (((d0 >> 7) & 7) << 4);
  const int srow = lg0 >> 6;
  const int scol = (lg0 & 63) >> 1;
  const int swk = ((lane >> 1) & 7) << 4;
  const int ar = wr * 64 + x, br = wc * 64 + x;

  for (int kt = 0; kt < 16; ++kt) {
    const int kofs = kt * 32;
    __syncthreads();
    #pragma unroll
    for (int r = 0; r < 2; ++r) {
      const int row  = r * 64 + srow;
      const int ldst = r * 4096 + wid * 1024;
      const size_t ga = (size_t)(rowA + row) * 512 + kofs + scol;
      const size_t gb = (size_t)(rowB + row) * 512 + kofs + scol;
      gld16(Ah + ga, (u16*)(sm + ldst));
      gld16(Al + ga, (u16*)(sm + 8192 + ldst));
      gld16(Bh + gb, (u16*)(sm + 16384 + ldst));
      gld16(Bl + gb, (u16*)(sm + 24576 + ldst));
    }
    __syncthreads();
    bf16x8 a_h[4], a_l[4], b_h[4], b_l[4];
    #pragma unroll
    for (int i = 0; i < 4; ++i) {
      const int off = ((ar + i * 16) * 64 + h * 16) ^ swk;
      a_h[i] = *(const bf16x8*)(sm + off);
      a_l[i] = *(const bf16x8*)(sm + 8192 + off);
    }
    #pragma unroll
    for (int j = 0; j < 4; ++j) {
      const int off = ((br + j * 16) * 64 + h * 16) ^ swk;
      b_h[j] = *(const bf16x8*)(sm + 16384 + off);
      b_l[j] = *(const bf16x8*)(sm + 24576 + off);
    }
    #pragma unroll
    for (int i = 0; i < 4; ++i)
      #pragma unroll
      for (int j = 0; j < 4; ++j) {
        acc[i][j] = MFMA(a_h[i], b_h[j], acc[i][j]);
        acc[i][j] = MFMA(a_h[i], b_l[j], acc[i][j]);
        acc[i][j] = MFMA(a_l[i], b_h[j], acc[i][j]);
      }
  }
}

// ---------------- QKV projection -------------------------------------------
__global__ __launch_bounds__(256) void k_gemm_qkv(
    const u16* __restrict__ Ah, const u16* __restrict__ Al,
    const u16* __restrict__ Bh, const u16* __restrict__ Bl,
    u16* __restrict__ Qh, u16* __restrict__ Ql,
    u16* __restrict__ Kh, u16* __restrict__ Kl, u16* __restrict__ Vt) {
  __shared__ __align__(1024) char sm[32768];
  const int tid = threadIdx.x, lane = tid & 63, wid = tid >> 6;
  const int x = lane & 15, h = lane >> 4;
  const int wr = wid >> 1, wc = wid & 1;
  const int rowA = blockIdx.x * 128, rowB = blockIdx.y * 128;
  f32x4 acc[4][4] = {};
  gemm_core(Ah, Al, Bh, Bl, sm, rowA, rowB, tid, acc);

  #pragma unroll
  for (int i = 0; i < 4; ++i)
    #pragma unroll
    for (int j = 0; j < 4; ++j) {
      const int n = rowB + wc * 64 + j * 16 + x;
      const int which = n >> 9;
      const int hh = (n >> 6) & 7, d = n & 63;
      const int m0 = rowA + wr * 64 + i * 16 + h * 4;
      const int b = m0 >> 11, is0 = m0 & 2047;
      if (which == 0) {
        #pragma unroll
        for (int r = 0; r < 4; ++r) {
          u16 hi, lo; splitbf(acc[i][j][r] * QSCALE, hi, lo);
          const size_t idx = ((size_t)((b * 8 + hh) * 2048 + is0 + r)) * 64 + d;
          Qh[idx] = hi; Ql[idx] = lo;
        }
      } else if (which == 1) {
        #pragma unroll
        for (int r = 0; r < 4; ++r) {
          u16 hi, lo; splitbf(acc[i][j][r], hi, lo);
          const size_t idx = ((size_t)((b * 8 + hh) * 2048 + is0 + r)) * 64 + d;
          Kh[idx] = hi; Kl[idx] = lo;
        }
      } else {
        s16x4 vv;
        #pragma unroll
        for (int r = 0; r < 4; ++r) vv[r] = (short)f2bf(acc[i][j][r]);
        *(s16x4*)&Vt[((size_t)((b * 8 + hh) * 64 + d)) * 2048 + is0] = vv;
      }
    }
}

// ---------------- output projection ---------------------------------------
__global__ __launch_bounds__(256) void k_gemm_out(
    const u16* __restrict__ Ah, const u16* __restrict__ Al,
    const u16* __restrict__ Bh, const u16* __restrict__ Bl,
    const float* __restrict__ bias, float* __restrict__ out) {
  __shared__ __align__(1024) char sm[32768];
  const int tid = threadIdx.x, lane = tid & 63, wid = tid >> 6;
  const int x = lane & 15, h = lane >> 4;
  const int wr = wid >> 1, wc = wid & 1;
  const int rowA = blockIdx.x * 128, rowB = blockIdx.y * 128;
  f32x4 acc[4][4] = {};
  gemm_core(Ah, Al, Bh, Bl, sm, rowA, rowB, tid, acc);

  #pragma unroll
  for (int i = 0; i < 4; ++i)
    #pragma unroll
    for (int j = 0; j < 4; ++j) {
      const int n = rowB + wc * 64 + j * 16 + x;
      #pragma unroll
      for (int r = 0; r < 4; ++r) {
        const int m = rowA + wr * 64 + i * 16 + h * 4 + r;
        out[(size_t)m * 512 + n] = acc[i][j][r] + bias[n];
      }
    }
}

// ---------------- flash attention ------------------------------------------
// Grid 512 blocks (XCD-swizzled), 512 thr = 8 waves x 16 Q-rows. KV tile 64.
// Swapped QK^T: lane (x,h) holds S[k=c*16+4h+r][q=x] -> per-lane softmax.
// P: cvt_pk -> 16x ds_bpermute into PV A-frags. Defer-rescale THR=7 (log2).
// LDS: buf0 {KH 0, KL 8K, V 16K}, buf1 {24K, 32K, 40K}. 48KB total.
__global__ __launch_bounds__(512) void k_attn(
    const u16* __restrict__ Qh, const u16* __restrict__ Ql,
    const u16* __restrict__ Kh, const u16* __restrict__ Kl,
    const u16* __restrict__ Vt,
    u16* __restrict__ AOh, u16* __restrict__ AOl) {
  __shared__ __align__(1024) char sm[49152];
  const int tid = threadIdx.x, wid = tid >> 6, lane = tid & 63;
  const int x = lane & 15, h = lane >> 4;

  // XCD-aware swizzle: 4 consecutive bh per XCD (KV set 3MB < 4MB L2)
  const int fid = blockIdx.x + blockIdx.y * 16;
  const int sw = (fid & 7) * 64 + (fid >> 3);
  const int qb = sw & 15, bh = sw >> 4;

  const size_t base = (size_t)bh * 2048 * 64;   // Q/K [bh][2048][64]; Vt [bh][64][2048]
  const int qr0 = qb * 128 + wid * 16;

  bf16x8 qh[2], ql[2];
  {
    const size_t rq = base + (size_t)(qr0 + x) * 64 + h * 8;
    qh[0] = *(const bf16x8*)&Qh[rq];      qh[1] = *(const bf16x8*)&Qh[rq + 32];
    ql[0] = *(const bf16x8*)&Ql[rq];      ql[1] = *(const bf16x8*)&Ql[rq + 32];
  }

  // staging map (linear dest, pre-swizzled source)
  const int dest = wid * 1024 + lane * 16;
  const int lg = dest ^ (((dest >> 7) & 7) << 4);
  const int sks = lg >> 12, srw = (lg >> 6) & 63, sco = (lg >> 1) & 31;
  const size_t offK = (size_t)srw * 64 + sks * 32 + sco;
  const size_t offV = (size_t)srw * 2048 + sks * 32 + sco;

  const int swk = ((lane >> 1) & 7) << 4;   // read xor for 64B-row tiles

  // bpermute addresses
  const int adrA = (x + 32 * (h & 1)) * 4;  // P redistribution, u<2
  const int adrB = adrA + 64;               // u>=2
  int aQ[4];
  #pragma unroll
  for (int r = 0; r < 4; ++r) aQ[r] = (20 * h + r) * 4;  // row 4h+r, copy h

  float mrun = -INFINITY, srun = 0.f;       // per-lane row q = x
  f32x4 o[4] = {};

  {  // stage tile 0 -> buf0
    char* lb = sm + wid * 1024;
    gld16(Kh + base + offK, (u16*)lb);
    gld16(Kl + base + offK, (u16*)(lb + 8192));
    gld16(Vt + base + offV, (u16*)(lb + 16384));
  }

  for (int kv = 0; kv < 32; ++kv) {
    const int bb = (kv & 1) * 24576;
    __builtin_amdgcn_s_barrier();
    if (kv < 31) {
      const size_t kvb = (size_t)(kv + 1) * 64;
      char* lb = sm + (24576 - bb) + wid * 1024;
      gld16(Kh + base + kvb * 64 + offK, (u16*)lb);
      gld16(Kl + base + kvb * 64 + offK, (u16*)(lb + 8192));
      gld16(Vt + base + kvb + offV, (u16*)(lb + 16384));
      asm volatile("s_waitcnt vmcnt(3)" ::: "memory");
    } else {
      asm volatile("s_waitcnt vmcnt(0)" ::: "memory");
    }
    __builtin_amdgcn_s_barrier();

    // ---- S^T = K Q^T (swapped; Q pre-scaled by 0.125*log2e), 3-term split
    f32x4 s4[4] = {};
    #pragma unroll
    for (int c = 0; c < 4; ++c)
      #pragma unroll
      for (int ks = 0; ks < 2; ++ks) {
        const int off = (bb + ks * 4096 + (c * 16 + x) * 64 + h * 16) ^ swk;
        bf16x8 kh_ = *(const bf16x8*)(sm + off);
        bf16x8 kl_ = *(const bf16x8*)(sm + off + 8192);
        s4[c] = MFMA(kh_, qh[ks], s4[c]);
        s4[c] = MFMA(kh_, ql[ks], s4[c]);
        s4[c] = MFMA(kl_, qh[ks], s4[c]);
      }

    // ---- per-lane row max (16 local values) + 2-shfl cross reduce
    float pm = fmaxf(fmaxf(fmaxf(s4[0][0], s4[0][1]), fmaxf(s4[0][2], s4[0][3])),
               fmaxf(fmaxf(fmaxf(s4[1][0], s4[1][1]), fmaxf(s4[1][2], s4[1][3])),
               fmaxf(fmaxf(fmaxf(s4[2][0], s4[2][1]), fmaxf(s4[2][2], s4[2][3])),
                     fmaxf(fmaxf(s4[3][0], s4[3][1]), fmaxf(s4[3][2], s4[3][3])))));
    pm = fmaxf(pm, __shfl_xor(pm, 16, 64));
    pm = fmaxf(pm, __shfl_xor(pm, 32, 64));

    // ---- defer-rescale: only when max grows past THR=7 (P bounded by 128)
    if (__any(pm > mrun + 7.0f)) {
      float mnew = fmaxf(mrun, pm);
      float scl = fexp2(mrun - mnew);
      srun *= scl;
      mrun = mnew;
      float sq[4];
      #pragma unroll
      for (int r = 0; r < 4; ++r)
        sq[r] = u2f((unsigned)__builtin_amdgcn_ds_bpermute(aQ[r], (int)f2u(scl)));
      #pragma unroll
      for (int dfr = 0; dfr < 4; ++dfr)
        #pragma unroll
        for (int r = 0; r < 4; ++r) o[dfr][r] *= sq[r];
    }

    // ---- P = exp2(S - mrun), pack pairs to bf16, accumulate ROUNDED sum
    int pk[4][2];
    #pragma unroll
    for (int c = 0; c < 4; ++c)
      #pragma unroll
      for (int m = 0; m < 2; ++m) {
        float p0 = fexp2(s4[c][2 * m] - mrun);
        float p1 = fexp2(s4[c][2 * m + 1] - mrun);
        int w = cvtpk(p0, p1);
        pk[c][m] = w;
        srun += u2f((unsigned)w << 16) + u2f((unsigned)w & 0xFFFF0000u);
      }

    // ---- redistribute P into PV A-frags: 16 bpermute + 8 select
    bf16x8 pa[2];
    #pragma unroll
    for (int ks2 = 0; ks2 < 2; ++ks2) {
      union { int w[4]; bf16x8 v; } uu;
      #pragma unroll
      for (int u = 0; u < 4; ++u) {
        const int adr = (u < 2) ? adrA : adrB;
        int r0 = __builtin_amdgcn_ds_bpermute(adr, pk[2 * ks2][u & 1]);
        int r1 = __builtin_amdgcn_ds_bpermute(adr, pk[2 * ks2 + 1][u & 1]);
        uu.w[u] = (h >= 2) ? r1 : r0;
      }
      pa[ks2] = uu.v;
    }

    // ---- PV
    #pragma unroll
    for (int ks2 = 0; ks2 < 2; ++ks2)
      #pragma unroll
      for (int dfr = 0; dfr < 4; ++dfr) {
        const int offv = (bb + 16384 + ks2 * 4096 + (dfr * 16 + x) * 64 + h * 16)
                         ^ swk;
        bf16x8 vb = *(const bf16x8*)(sm + offv);
        o[dfr] = MFMA(pa[ks2], vb, o[dfr]);
      }
  }

  // ---- final: reduce srun over h-copies, redistribute to o-rows, write AO
  srun += __shfl_xor(srun, 16, 64);
  srun += __shfl_xor(srun, 32, 64);
  float inv[4];
  #pragma unroll
  for (int r = 0; r < 4; ++r)
    inv[r] = 1.0f /
        u2f((unsigned)__builtin_amdgcn_ds_bpermute(aQ[r], (int)f2u(srun)));

  const int b = bh >> 3, hd = bh & 7;
  #pragma unroll
  for (int r = 0; r < 4; ++r) {
    const int row = qr0 + h * 4 + r;
    #pragma unroll
    for (int dfr = 0; dfr < 4; ++dfr) {
      const int d = dfr * 16 + x;
      const size_t idx = ((size_t)(b * 2048 + row)) * 512 + hd * 64 + d;
      u16 hi, lo; splitbf(o[dfr][r] * inv[r], hi, lo);
      AOh[idx] = hi; AOl[idx] = lo;
    }
  }
}

// ---------------------------------------------------------------------------
extern "C" void kernel_launch(void* const* d_in, const int* in_sizes, int n_in,
                              void* d_out, int out_size, void* d_ws, size_t ws_size,
                              hipStream_t stream) {
  const float* x    = (const float*)d_in[0];
  const float* wqkv = (const float*)d_in[1];
  const float* wout = (const float*)d_in[2];
  const float* bout = (const float*)d_in[3];
  float* out = (float*)d_out;

  char* w = (char*)d_ws;
  u16* xh  = (u16*)(w + 0);           // 8192x512 bf16 hi
  u16* xl  = (u16*)(w + 8388608);
  u16* wqh = (u16*)(w + 16777216);    // WqkvT [1536][512]
  u16* wql = (u16*)(w + 18350080);
  u16* woh = (u16*)(w + 19922944);    // WoutT [512][512]
  u16* wol = (u16*)(w + 20447232);
  u16* Qh  = (u16*)(w + 20971520);    // [32][2048][64]
  u16* Ql  = (u16*)(w + 29360128);
  u16* Kh  = (u16*)(w + 37748736);
  u16* Kl  = (u16*)(w + 46137344);
  u16* Vt  = (u16*)(w + 54525952);    // [32][64][2048]
  u16* AOh = (u16*)(w + 62914560);    // [8192][512]
  u16* AOl = (u16*)(w + 71303168);    // total 79691776 bytes

  k_split <<<4194304 / 256, 256, 0, stream>>>(x, xh, xl, 4194304);
  k_tsplit<<< 786432 / 256, 256, 0, stream>>>(wqkv, wqh, wql, 1536, 786432);
  k_tsplit<<< 262144 / 256, 256, 0, stream>>>(wout, woh, wol, 512, 262144);
  k_gemm_qkv<<<dim3(64, 12), 256, 0, stream>>>(xh, xl, wqh, wql,
                                               Qh, Ql, Kh, Kl, Vt);
  k_attn<<<dim3(16, 32), 512, 0, stream>>>(Qh, Ql, Kh, Kl, Vt, AOh, AOl);
  k_gemm_out<<<dim3(64, 4), 256, 0, stream>>>(AOh, AOl, woh, wol, bout, out);
}

// Round 4
// 168.919 us; speedup vs baseline: 1.3782x; 1.0377x over previous
//
#include <hip/hip_runtime.h>
#include <hip/hip_bf16.h>
#include <math.h>
#include <stdint.h>

// ---------------------------------------------------------------------------
// Attention (B=4, N=2048, D=512, H=8, Dh=64) for MI355X.
// Precision: split-bf16 (hi/lo) 3-term MFMA for x@Wqkv, QK^T, AO@Wout;
// plain bf16 P,V in PV (softmax-attenuated error).
// R4: MFMA ones-column row-sum (srun VALU path eliminated), max3 row-max,
// base+imm LDS addressing, setprio around MFMA clusters, float4 k_split.
// ---------------------------------------------------------------------------

typedef unsigned short u16;
typedef __attribute__((ext_vector_type(4))) float f32x4;
typedef __attribute__((ext_vector_type(8))) short bf16x8;   // 8 bf16 = 4 VGPRs
typedef __attribute__((ext_vector_type(4))) short s16x4;

#define AS1 __attribute__((address_space(1)))
#define AS3 __attribute__((address_space(3)))
#define MFMA(a, b, c) __builtin_amdgcn_mfma_f32_16x16x32_bf16(a, b, c, 0, 0, 0)
#define QSCALE 0.180336880f   /* 0.125 * log2(e): logits in log2 domain */

__device__ __forceinline__ u16 f2bf(float f) {
  union { float f; unsigned u; } v; v.f = f;
  unsigned r = v.u + 0x7FFFu + ((v.u >> 16) & 1u);   // RNE
  return (u16)(r >> 16);
}
__device__ __forceinline__ float bf2f(u16 b) {
  union { unsigned u; float f; } v; v.u = ((unsigned)b) << 16; return v.f;
}
__device__ __forceinline__ void splitbf(float x, u16& hi, u16& lo) {
  hi = f2bf(x); lo = f2bf(x - bf2f(hi));
}
__device__ __forceinline__ void gld16(const u16* g, u16* l) {
  __builtin_amdgcn_global_load_lds((const AS1 void*)g, (AS3 void*)l, 16, 0, 0);
}
__device__ __forceinline__ float u2f(unsigned u) {
  union { unsigned u; float f; } v; v.u = u; return v.f;
}
__device__ __forceinline__ unsigned f2u(float f) {
  union { float f; unsigned u; } v; v.f = f; return v.u;
}
__device__ __forceinline__ int cvtpk(float lo, float hi) {
  int r; asm("v_cvt_pk_bf16_f32 %0, %1, %2" : "=v"(r) : "v"(lo), "v"(hi));
  return r;
}
__device__ __forceinline__ float fexp2(float x) {
  float r; asm("v_exp_f32 %0, %1" : "=v"(r) : "v"(x));
  return r;
}

// ---------------- prep kernels -------------------------------------------
__global__ void k_split(const float* __restrict__ s, u16* __restrict__ h,
                        u16* __restrict__ l, int n) {
  int i = (blockIdx.x * 256 + threadIdx.x) * 4;
  if (i < n) {
    f32x4 v = *(const f32x4*)&s[i];
    s16x4 hh, ll;
    #pragma unroll
    for (int j = 0; j < 4; ++j) {
      u16 a, b; splitbf(v[j], a, b);
      hh[j] = (short)a; ll[j] = (short)b;
    }
    *(s16x4*)&h[i] = hh;
    *(s16x4*)&l[i] = ll;
  }
}

// src [512][N] row-major -> dst [N][512] (transposed), split hi/lo
__global__ void k_tsplit(const float* __restrict__ s, u16* __restrict__ h,
                         u16* __restrict__ l, int N, int total) {
  int i = blockIdx.x * 256 + threadIdx.x;          // i = n*512 + k
  if (i < total) {
    int n = i >> 9, k = i & 511;
    u16 a, b; splitbf(s[(size_t)k * N + n], a, b);
    h[i] = a; l[i] = b;
  }
}

// ---------------- shared GEMM core: C[128x128] tile, K=512, BK=32 ----------
__device__ __forceinline__ void gemm_core(
    const u16* __restrict__ Ah, const u16* __restrict__ Al,
    const u16* __restrict__ Bh, const u16* __restrict__ Bl,
    char* sm, int rowA, int rowB, int tid, f32x4 (&acc)[4][4]) {
  const int wid = tid >> 6, lane = tid & 63;
  const int x = lane & 15, h = lane >> 4;
  const int wr = wid >> 1, wc = wid & 1;
  const int d0 = wid * 1024 + lane * 16;
  const int lg0 = d0 ^ (((d0 >> 7) & 7) << 4);
  const int srow = lg0 >> 6;
  const int scol = (lg0 & 63) >> 1;
  const int swk = ((lane >> 1) & 7) << 4;
  const char* smA = sm + (((wr * 64 + x) * 64 + h * 16) ^ swk);
  const char* smB = sm + (((wc * 64 + x) * 64 + h * 16) ^ swk);

  for (int kt = 0; kt < 16; ++kt) {
    const int kofs = kt * 32;
    __syncthreads();
    #pragma unroll
    for (int r = 0; r < 2; ++r) {
      const int row  = r * 64 + srow;
      const int ldst = r * 4096 + wid * 1024;
      const size_t ga = (size_t)(rowA + row) * 512 + kofs + scol;
      const size_t gb = (size_t)(rowB + row) * 512 + kofs + scol;
      gld16(Ah + ga, (u16*)(sm + ldst));
      gld16(Al + ga, (u16*)(sm + 8192 + ldst));
      gld16(Bh + gb, (u16*)(sm + 16384 + ldst));
      gld16(Bl + gb, (u16*)(sm + 24576 + ldst));
    }
    __syncthreads();
    bf16x8 a_h[4], a_l[4], b_h[4], b_l[4];
    #pragma unroll
    for (int i = 0; i < 4; ++i) {
      a_h[i] = *(const bf16x8*)(smA + i * 1024);
      a_l[i] = *(const bf16x8*)(smA + 8192 + i * 1024);
    }
    #pragma unroll
    for (int j = 0; j < 4; ++j) {
      b_h[j] = *(const bf16x8*)(smB + 16384 + j * 1024);
      b_l[j] = *(const bf16x8*)(smB + 24576 + j * 1024);
    }
    __builtin_amdgcn_s_setprio(1);
    #pragma unroll
    for (int i = 0; i < 4; ++i)
      #pragma unroll
      for (int j = 0; j < 4; ++j) {
        acc[i][j] = MFMA(a_h[i], b_h[j], acc[i][j]);
        acc[i][j] = MFMA(a_h[i], b_l[j], acc[i][j]);
        acc[i][j] = MFMA(a_l[i], b_h[j], acc[i][j]);
      }
    __builtin_amdgcn_s_setprio(0);
  }
}

// ---------------- QKV projection -------------------------------------------
__global__ __launch_bounds__(256) void k_gemm_qkv(
    const u16* __restrict__ Ah, const u16* __restrict__ Al,
    const u16* __restrict__ Bh, const u16* __restrict__ Bl,
    u16* __restrict__ Qh, u16* __restrict__ Ql,
    u16* __restrict__ Kh, u16* __restrict__ Kl, u16* __restrict__ Vt) {
  __shared__ __align__(1024) char sm[32768];
  const int tid = threadIdx.x, lane = tid & 63, wid = tid >> 6;
  const int x = lane & 15, h = lane >> 4;
  const int wr = wid >> 1, wc = wid & 1;
  const int rowA = blockIdx.x * 128, rowB = blockIdx.y * 128;
  f32x4 acc[4][4] = {};
  gemm_core(Ah, Al, Bh, Bl, sm, rowA, rowB, tid, acc);

  #pragma unroll
  for (int i = 0; i < 4; ++i)
    #pragma unroll
    for (int j = 0; j < 4; ++j) {
      const int n = rowB + wc * 64 + j * 16 + x;
      const int which = n >> 9;
      const int hh = (n >> 6) & 7, d = n & 63;
      const int m0 = rowA + wr * 64 + i * 16 + h * 4;
      const int b = m0 >> 11, is0 = m0 & 2047;
      if (which == 0) {
        #pragma unroll
        for (int r = 0; r < 4; ++r) {
          u16 hi, lo; splitbf(acc[i][j][r] * QSCALE, hi, lo);
          const size_t idx = ((size_t)((b * 8 + hh) * 2048 + is0 + r)) * 64 + d;
          Qh[idx] = hi; Ql[idx] = lo;
        }
      } else if (which == 1) {
        #pragma unroll
        for (int r = 0; r < 4; ++r) {
          u16 hi, lo; splitbf(acc[i][j][r], hi, lo);
          const size_t idx = ((size_t)((b * 8 + hh) * 2048 + is0 + r)) * 64 + d;
          Kh[idx] = hi; Kl[idx] = lo;
        }
      } else {
        s16x4 vv;
        #pragma unroll
        for (int r = 0; r < 4; ++r) vv[r] = (short)f2bf(acc[i][j][r]);
        *(s16x4*)&Vt[((size_t)((b * 8 + hh) * 64 + d)) * 2048 + is0] = vv;
      }
    }
}

// ---------------- output projection ---------------------------------------
__global__ __launch_bounds__(256) void k_gemm_out(
    const u16* __restrict__ Ah, const u16* __restrict__ Al,
    const u16* __restrict__ Bh, const u16* __restrict__ Bl,
    const float* __restrict__ bias, float* __restrict__ out) {
  __shared__ __align__(1024) char sm[32768];
  const int tid = threadIdx.x, lane = tid & 63, wid = tid >> 6;
  const int x = lane & 15, h = lane >> 4;
  const int wr = wid >> 1, wc = wid & 1;
  const int rowA = blockIdx.x * 128, rowB = blockIdx.y * 128;
  f32x4 acc[4][4] = {};
  gemm_core(Ah, Al, Bh, Bl, sm, rowA, rowB, tid, acc);

  #pragma unroll
  for (int i = 0; i < 4; ++i)
    #pragma unroll
    for (int j = 0; j < 4; ++j) {
      const int n = rowB + wc * 64 + j * 16 + x;
      #pragma unroll
      for (int r = 0; r < 4; ++r) {
        const int m = rowA + wr * 64 + i * 16 + h * 4 + r;
        out[(size_t)m * 512 + n] = acc[i][j][r] + bias[n];
      }
    }
}

// ---------------- flash attention ------------------------------------------
// Grid 512 blocks (XCD-swizzled), 512 thr = 8 waves x 16 Q-rows. KV tile 64.
// Swapped QK^T: lane (x,h) holds S^T[k=c*16+4h+r][q=x] -> per-lane softmax.
// P: cvt_pk -> 16x ds_bpermute into PV A-frags. Defer-rescale THR=7 (log2).
// Row-sum via MFMA(P, ones) -> osum (no srun VALU path).
// LDS: buf0 {KH 0, KL 8K, V 16K}, buf1 {24K, 32K, 40K}. 48KB total.
__global__ __launch_bounds__(512) void k_attn(
    const u16* __restrict__ Qh, const u16* __restrict__ Ql,
    const u16* __restrict__ Kh, const u16* __restrict__ Kl,
    const u16* __restrict__ Vt,
    u16* __restrict__ AOh, u16* __restrict__ AOl) {
  __shared__ __align__(1024) char sm[49152];
  const int tid = threadIdx.x, wid = tid >> 6, lane = tid & 63;
  const int x = lane & 15, h = lane >> 4;

  // XCD-aware swizzle: 4 consecutive bh per XCD (KV set 3MB < 4MB L2)
  const int fid = blockIdx.x + blockIdx.y * 16;
  const int sw = (fid & 7) * 64 + (fid >> 3);
  const int qb = sw & 15, bh = sw >> 4;

  const size_t base = (size_t)bh * 2048 * 64;   // Q/K [bh][2048][64]; Vt [bh][64][2048]
  const int qr0 = qb * 128 + wid * 16;

  bf16x8 qh[2], ql[2];
  {
    const size_t rq = base + (size_t)(qr0 + x) * 64 + h * 8;
    qh[0] = *(const bf16x8*)&Qh[rq];      qh[1] = *(const bf16x8*)&Qh[rq + 32];
    ql[0] = *(const bf16x8*)&Ql[rq];      ql[1] = *(const bf16x8*)&Ql[rq + 32];
  }

  bf16x8 ones;
  #pragma unroll
  for (int j = 0; j < 8; ++j) ones[j] = (short)0x3F80;   // bf16 1.0

  // staging map (linear dest, pre-swizzled source)
  const int dest = wid * 1024 + lane * 16;
  const int lg = dest ^ (((dest >> 7) & 7) << 4);
  const int sks = lg >> 12, srw = (lg >> 6) & 63, sco = (lg >> 1) & 31;
  const size_t offK = (size_t)srw * 64 + sks * 32 + sco;
  const size_t offV = (size_t)srw * 2048 + sks * 32 + sco;

  const int swk = ((lane >> 1) & 7) << 4;   // read xor for 64B-row tiles
  const int rdo = (x * 64 + h * 16) ^ swk;  // per-lane read base offset

  // bpermute addresses
  const int adrA = (x + 32 * (h & 1)) * 4;  // P redistribution, u<2
  const int adrB = adrA + 64;               // u>=2
  int aQ[4];
  #pragma unroll
  for (int r = 0; r < 4; ++r) aQ[r] = (20 * h + r) * 4;  // row 4h+r, copy h

  float mrun = -INFINITY;                    // per-lane row q = x
  f32x4 o[4] = {};
  f32x4 os = {};                             // row-sums (rows q = 4h+r)

  {  // stage tile 0 -> buf0
    char* lb = sm + wid * 1024;
    gld16(Kh + base + offK, (u16*)lb);
    gld16(Kl + base + offK, (u16*)(lb + 8192));
    gld16(Vt + base + offV, (u16*)(lb + 16384));
  }

  for (int kv = 0; kv < 32; ++kv) {
    const int bb = (kv & 1) * 24576;
    __builtin_amdgcn_s_barrier();
    if (kv < 31) {
      const size_t kvb = (size_t)(kv + 1) * 64;
      char* lb = sm + (24576 - bb) + wid * 1024;
      gld16(Kh + base + kvb * 64 + offK, (u16*)lb);
      gld16(Kl + base + kvb * 64 + offK, (u16*)(lb + 8192));
      gld16(Vt + base + kvb + offV, (u16*)(lb + 16384));
      asm volatile("s_waitcnt vmcnt(3)" ::: "memory");
    } else {
      asm volatile("s_waitcnt vmcnt(0)" ::: "memory");
    }
    __builtin_amdgcn_s_barrier();

    const char* smb = sm + bb + rdo;          // all reads = smb + const imm

    // ---- S^T = K Q^T (swapped; Q pre-scaled by 0.125*log2e), 3-term split
    f32x4 s4[4] = {};
    __builtin_amdgcn_s_setprio(1);
    #pragma unroll
    for (int c = 0; c < 4; ++c)
      #pragma unroll
      for (int ks = 0; ks < 2; ++ks) {
        bf16x8 kh_ = *(const bf16x8*)(smb + ks * 4096 + c * 1024);
        bf16x8 kl_ = *(const bf16x8*)(smb + 8192 + ks * 4096 + c * 1024);
        s4[c] = MFMA(kh_, qh[ks], s4[c]);
        s4[c] = MFMA(kh_, ql[ks], s4[c]);
        s4[c] = MFMA(kl_, qh[ks], s4[c]);
      }
    __builtin_amdgcn_s_setprio(0);

    // ---- per-lane row max: max3 tree (8 ops) + 2-shfl cross reduce
    float m0 = fmaxf(fmaxf(s4[0][0], s4[0][1]), s4[0][2]);
    float m1 = fmaxf(fmaxf(s4[0][3], s4[1][0]), s4[1][1]);
    float m2 = fmaxf(fmaxf(s4[1][2], s4[1][3]), s4[2][0]);
    float m3 = fmaxf(fmaxf(s4[2][1], s4[2][2]), s4[2][3]);
    float m4 = fmaxf(fmaxf(s4[3][0], s4[3][1]), s4[3][2]);
    float m5 = fmaxf(fmaxf(m0, m1), m2);
    float pm = fmaxf(fmaxf(fmaxf(m3, m4), s4[3][3]), m5);
    pm = fmaxf(pm, __shfl_xor(pm, 16, 64));
    pm = fmaxf(pm, __shfl_xor(pm, 32, 64));

    // ---- defer-rescale: only when max grows past THR=7 (P bounded by 128)
    if (__any(pm > mrun + 7.0f)) {
      float mnew = fmaxf(mrun, pm);
      float scl = fexp2(mrun - mnew);
      mrun = mnew;
      float sq[4];
      #pragma unroll
      for (int r = 0; r < 4; ++r)
        sq[r] = u2f((unsigned)__builtin_amdgcn_ds_bpermute(aQ[r], (int)f2u(scl)));
      #pragma unroll
      for (int dfr = 0; dfr < 4; ++dfr)
        #pragma unroll
        for (int r = 0; r < 4; ++r) o[dfr][r] *= sq[r];
      #pragma unroll
      for (int r = 0; r < 4; ++r) os[r] *= sq[r];
    }

    // ---- P = exp2(S - mrun), pack pairs to bf16
    int pk[4][2];
    #pragma unroll
    for (int c = 0; c < 4; ++c)
      #pragma unroll
      for (int m = 0; m < 2; ++m) {
        float p0 = fexp2(s4[c][2 * m] - mrun);
        float p1 = fexp2(s4[c][2 * m + 1] - mrun);
        pk[c][m] = cvtpk(p0, p1);
      }

    // ---- redistribute P into PV A-frags: 16 bpermute + 8 select
    bf16x8 pa[2];
    #pragma unroll
    for (int ks2 = 0; ks2 < 2; ++ks2) {
      union { int w[4]; bf16x8 v; } uu;
      #pragma unroll
      for (int u = 0; u < 4; ++u) {
        const int adr = (u < 2) ? adrA : adrB;
        int r0 = __builtin_amdgcn_ds_bpermute(adr, pk[2 * ks2][u & 1]);
        int r1 = __builtin_amdgcn_ds_bpermute(adr, pk[2 * ks2 + 1][u & 1]);
        uu.w[u] = (h >= 2) ? r1 : r0;
      }
      pa[ks2] = uu.v;
    }

    // ---- PV + MFMA row-sum (ones column)
    __builtin_amdgcn_s_setprio(1);
    #pragma unroll
    for (int ks2 = 0; ks2 < 2; ++ks2) {
      #pragma unroll
      for (int dfr = 0; dfr < 4; ++dfr) {
        bf16x8 vb = *(const bf16x8*)(smb + 16384 + ks2 * 4096 + dfr * 1024);
        o[dfr] = MFMA(pa[ks2], vb, o[dfr]);
      }
      os = MFMA(pa[ks2], ones, os);
    }
    __builtin_amdgcn_s_setprio(0);
  }

  // ---- normalize (os[r] is rowsum for q = 4h+r), split-write AO [8192][512]
  const int b = bh >> 3, hd = bh & 7;
  #pragma unroll
  for (int r = 0; r < 4; ++r) {
    const float inv = 1.0f / os[r];
    const int row = qr0 + h * 4 + r;
    #pragma unroll
    for (int dfr = 0; dfr < 4; ++dfr) {
      const int d = dfr * 16 + x;
      const size_t idx = ((size_t)(b * 2048 + row)) * 512 + hd * 64 + d;
      u16 hi, lo; splitbf(o[dfr][r] * inv, hi, lo);
      AOh[idx] = hi; AOl[idx] = lo;
    }
  }
}

// ---------------------------------------------------------------------------
extern "C" void kernel_launch(void* const* d_in, const int* in_sizes, int n_in,
                              void* d_out, int out_size, void* d_ws, size_t ws_size,
                              hipStream_t stream) {
  const float* x    = (const float*)d_in[0];
  const float* wqkv = (const float*)d_in[1];
  const float* wout = (const float*)d_in[2];
  const float* bout = (const float*)d_in[3];
  float* out = (float*)d_out;

  char* w = (char*)d_ws;
  u16* xh  = (u16*)(w + 0);           // 8192x512 bf16 hi
  u16* xl  = (u16*)(w + 8388608);
  u16* wqh = (u16*)(w + 16777216);    // WqkvT [1536][512]
  u16* wql = (u16*)(w + 18350080);
  u16* woh = (u16*)(w + 19922944);    // WoutT [512][512]
  u16* wol = (u16*)(w + 20447232);
  u16* Qh  = (u16*)(w + 20971520);    // [32][2048][64]
  u16* Ql  = (u16*)(w + 29360128);
  u16* Kh  = (u16*)(w + 37748736);
  u16* Kl  = (u16*)(w + 46137344);
  u16* Vt  = (u16*)(w + 54525952);    // [32][64][2048]
  u16* AOh = (u16*)(w + 62914560);    // [8192][512]
  u16* AOl = (u16*)(w + 71303168);    // total 79691776 bytes

  k_split <<<4194304 / 1024, 256, 0, stream>>>(x, xh, xl, 4194304);
  k_tsplit<<< 786432 / 256, 256, 0, stream>>>(wqkv, wqh, wql, 1536, 786432);
  k_tsplit<<< 262144 / 256, 256, 0, stream>>>(wout, woh, wol, 512, 262144);
  k_gemm_qkv<<<dim3(64, 12), 256, 0, stream>>>(xh, xl, wqh, wql,
                                               Qh, Ql, Kh, Kl, Vt);
  k_attn<<<dim3(16, 32), 512, 0, stream>>>(Qh, Ql, Kh, Kl, Vt, AOh, AOl);
  k_gemm_out<<<dim3(64, 4), 256, 0, stream>>>(AOh, AOl, woh, wol, bout, out);
}

// Round 5
// 145.744 us; speedup vs baseline: 1.5974x; 1.1590x over previous
//
#include <hip/hip_runtime.h>
#include <hip/hip_bf16.h>
#include <math.h>
#include <stdint.h>

// ---------------------------------------------------------------------------
// Attention (B=4, N=2048, D=512, H=8, Dh=64) for MI355X.
// Precision plan (threshold 6.48e-3 absolute):
//   x@Wqkv Q/K cols: 3-term split-bf16 MFMA; V cols: 1-term bf16.
//   QK^T: Q split (2-term), K plain bf16.  PV: bf16 P,V.
//   AO plain bf16; out GEMM 1-term bf16.
// R5: 2-term QK^T (no Kl), QBLK=64 4-wave attn blocks (grid 1024, 4/CU,
// 32KB LDS), AO un-split + 1-term out GEMM, V-region fast path in QKV GEMM.
// ---------------------------------------------------------------------------

typedef unsigned short u16;
typedef __attribute__((ext_vector_type(4))) float f32x4;
typedef __attribute__((ext_vector_type(8))) short bf16x8;   // 8 bf16 = 4 VGPRs
typedef __attribute__((ext_vector_type(4))) short s16x4;

#define AS1 __attribute__((address_space(1)))
#define AS3 __attribute__((address_space(3)))
#define MFMA(a, b, c) __builtin_amdgcn_mfma_f32_16x16x32_bf16(a, b, c, 0, 0, 0)
#define QSCALE 0.180336880f   /* 0.125 * log2(e): logits in log2 domain */

__device__ __forceinline__ u16 f2bf(float f) {
  union { float f; unsigned u; } v; v.f = f;
  unsigned r = v.u + 0x7FFFu + ((v.u >> 16) & 1u);   // RNE
  return (u16)(r >> 16);
}
__device__ __forceinline__ float bf2f(u16 b) {
  union { unsigned u; float f; } v; v.u = ((unsigned)b) << 16; return v.f;
}
__device__ __forceinline__ void splitbf(float x, u16& hi, u16& lo) {
  hi = f2bf(x); lo = f2bf(x - bf2f(hi));
}
__device__ __forceinline__ void gld16(const u16* g, u16* l) {
  __builtin_amdgcn_global_load_lds((const AS1 void*)g, (AS3 void*)l, 16, 0, 0);
}
__device__ __forceinline__ float u2f(unsigned u) {
  union { unsigned u; float f; } v; v.u = u; return v.f;
}
__device__ __forceinline__ unsigned f2u(float f) {
  union { float f; unsigned u; } v; v.f = f; return v.u;
}
__device__ __forceinline__ int cvtpk(float lo, float hi) {
  int r; asm("v_cvt_pk_bf16_f32 %0, %1, %2" : "=v"(r) : "v"(lo), "v"(hi));
  return r;
}
__device__ __forceinline__ float fexp2(float x) {
  float r; asm("v_exp_f32 %0, %1" : "=v"(r) : "v"(x));
  return r;
}

// ---------------- prep kernels -------------------------------------------
__global__ void k_split(const float* __restrict__ s, u16* __restrict__ h,
                        u16* __restrict__ l, int n) {
  int i = (blockIdx.x * 256 + threadIdx.x) * 4;
  if (i < n) {
    f32x4 v = *(const f32x4*)&s[i];
    s16x4 hh, ll;
    #pragma unroll
    for (int j = 0; j < 4; ++j) {
      u16 a, b; splitbf(v[j], a, b);
      hh[j] = (short)a; ll[j] = (short)b;
    }
    *(s16x4*)&h[i] = hh;
    *(s16x4*)&l[i] = ll;
  }
}

// src [512][N] row-major -> dst [N][512] (transposed), split hi/lo
__global__ void k_tsplit(const float* __restrict__ s, u16* __restrict__ h,
                         u16* __restrict__ l, int N, int total) {
  int i = blockIdx.x * 256 + threadIdx.x;          // i = n*512 + k
  if (i < total) {
    int n = i >> 9, k = i & 511;
    u16 a, b; splitbf(s[(size_t)k * N + n], a, b);
    h[i] = a; l[i] = b;
  }
}

// ---------------- shared GEMM core: C[128x128] tile, K=512, BK=32 ----------
// FAST: 1-term bf16 (hi only).  !FAST: 3-term split.
template <bool FAST>
__device__ __forceinline__ void gemm_core(
    const u16* __restrict__ Ah, const u16* __restrict__ Al,
    const u16* __restrict__ Bh, const u16* __restrict__ Bl,
    char* sm, int rowA, int rowB, int tid, f32x4 (&acc)[4][4]) {
  const int wid = tid >> 6, lane = tid & 63;
  const int x = lane & 15, h = lane >> 4;
  const int wr = wid >> 1, wc = wid & 1;
  const int d0 = wid * 1024 + lane * 16;
  const int lg0 = d0 ^ (((d0 >> 7) & 7) << 4);
  const int srow = lg0 >> 6;
  const int scol = (lg0 & 63) >> 1;
  const int swk = ((lane >> 1) & 7) << 4;
  const char* smA = sm + (((wr * 64 + x) * 64 + h * 16) ^ swk);
  const char* smB = sm + (((wc * 64 + x) * 64 + h * 16) ^ swk);

  for (int kt = 0; kt < 16; ++kt) {
    const int kofs = kt * 32;
    __syncthreads();
    #pragma unroll
    for (int r = 0; r < 2; ++r) {
      const int row  = r * 64 + srow;
      const int ldst = r * 4096 + wid * 1024;
      const size_t ga = (size_t)(rowA + row) * 512 + kofs + scol;
      const size_t gb = (size_t)(rowB + row) * 512 + kofs + scol;
      gld16(Ah + ga, (u16*)(sm + ldst));
      gld16(Bh + gb, (u16*)(sm + 16384 + ldst));
      if (!FAST) {
        gld16(Al + ga, (u16*)(sm + 8192 + ldst));
        gld16(Bl + gb, (u16*)(sm + 24576 + ldst));
      }
    }
    __syncthreads();
    bf16x8 a_h[4], a_l[4], b_h[4], b_l[4];
    #pragma unroll
    for (int i = 0; i < 4; ++i) {
      a_h[i] = *(const bf16x8*)(smA + i * 1024);
      if (!FAST) a_l[i] = *(const bf16x8*)(smA + 8192 + i * 1024);
    }
    #pragma unroll
    for (int j = 0; j < 4; ++j) {
      b_h[j] = *(const bf16x8*)(smB + 16384 + j * 1024);
      if (!FAST) b_l[j] = *(const bf16x8*)(smB + 24576 + j * 1024);
    }
    __builtin_amdgcn_s_setprio(1);
    #pragma unroll
    for (int i = 0; i < 4; ++i)
      #pragma unroll
      for (int j = 0; j < 4; ++j) {
        acc[i][j] = MFMA(a_h[i], b_h[j], acc[i][j]);
        if (!FAST) {
          acc[i][j] = MFMA(a_h[i], b_l[j], acc[i][j]);
          acc[i][j] = MFMA(a_l[i], b_h[j], acc[i][j]);
        }
      }
    __builtin_amdgcn_s_setprio(0);
  }
}

// ---------------- QKV projection -------------------------------------------
// n<512: Q (xQSCALE, split -> Qh/Ql [bh][n][64]); 512..1023: K -> bf16 Kb;
// >=1024: V -> Vt [bh][64][2048] bf16 (1-term fast path).
__global__ __launch_bounds__(256) void k_gemm_qkv(
    const u16* __restrict__ Ah, const u16* __restrict__ Al,
    const u16* __restrict__ Bh, const u16* __restrict__ Bl,
    u16* __restrict__ Qh, u16* __restrict__ Ql,
    u16* __restrict__ Kb, u16* __restrict__ Vt) {
  __shared__ __align__(1024) char sm[32768];
  const int tid = threadIdx.x, lane = tid & 63, wid = tid >> 6;
  const int x = lane & 15, h = lane >> 4;
  const int wr = wid >> 1, wc = wid & 1;
  const int rowA = blockIdx.x * 128, rowB = blockIdx.y * 128;
  f32x4 acc[4][4] = {};
  if (rowB >= 1024)
    gemm_core<true>(Ah, Al, Bh, Bl, sm, rowA, rowB, tid, acc);
  else
    gemm_core<false>(Ah, Al, Bh, Bl, sm, rowA, rowB, tid, acc);

  #pragma unroll
  for (int i = 0; i < 4; ++i)
    #pragma unroll
    for (int j = 0; j < 4; ++j) {
      const int n = rowB + wc * 64 + j * 16 + x;
      const int which = n >> 9;
      const int hh = (n >> 6) & 7, d = n & 63;
      const int m0 = rowA + wr * 64 + i * 16 + h * 4;
      const int b = m0 >> 11, is0 = m0 & 2047;
      if (which == 0) {
        #pragma unroll
        for (int r = 0; r < 4; ++r) {
          u16 hi, lo; splitbf(acc[i][j][r] * QSCALE, hi, lo);
          const size_t idx = ((size_t)((b * 8 + hh) * 2048 + is0 + r)) * 64 + d;
          Qh[idx] = hi; Ql[idx] = lo;
        }
      } else if (which == 1) {
        #pragma unroll
        for (int r = 0; r < 4; ++r) {
          const size_t idx = ((size_t)((b * 8 + hh) * 2048 + is0 + r)) * 64 + d;
          Kb[idx] = f2bf(acc[i][j][r]);
        }
      } else {
        s16x4 vv;
        #pragma unroll
        for (int r = 0; r < 4; ++r) vv[r] = (short)f2bf(acc[i][j][r]);
        *(s16x4*)&Vt[((size_t)((b * 8 + hh) * 64 + d)) * 2048 + is0] = vv;
      }
    }
}

// ---------------- output projection (1-term bf16) --------------------------
__global__ __launch_bounds__(256) void k_gemm_out(
    const u16* __restrict__ Ah, const u16* __restrict__ Bh,
    const float* __restrict__ bias, float* __restrict__ out) {
  __shared__ __align__(1024) char sm[32768];
  const int tid = threadIdx.x, lane = tid & 63, wid = tid >> 6;
  const int x = lane & 15, h = lane >> 4;
  const int wr = wid >> 1, wc = wid & 1;
  const int rowA = blockIdx.x * 128, rowB = blockIdx.y * 128;
  f32x4 acc[4][4] = {};
  gemm_core<true>(Ah, Ah, Bh, Bh, sm, rowA, rowB, tid, acc);

  #pragma unroll
  for (int i = 0; i < 4; ++i)
    #pragma unroll
    for (int j = 0; j < 4; ++j) {
      const int n = rowB + wc * 64 + j * 16 + x;
      #pragma unroll
      for (int r = 0; r < 4; ++r) {
        const int m = rowA + wr * 64 + i * 16 + h * 4 + r;
        out[(size_t)m * 512 + n] = acc[i][j][r] + bias[n];
      }
    }
}

// ---------------- flash attention ------------------------------------------
// Grid 1024 blocks (XCD-swizzled), 256 thr = 4 waves x 16 Q-rows (QBLK=64).
// KV tile 64.  Swapped QK^T: lane (x,h) holds S^T[k=c*16+4h+r][q=x].
// 2-term QK^T (Q split, K bf16).  P: cvt_pk -> 16x ds_bpermute into PV
// A-frags.  Defer-rescale THR=7 (log2).  Row-sum via MFMA(P, ones).
// LDS: buf {K 8K, V 8K} x2 = 32KB.
__global__ __launch_bounds__(256) void k_attn(
    const u16* __restrict__ Qh, const u16* __restrict__ Ql,
    const u16* __restrict__ Kb, const u16* __restrict__ Vt,
    u16* __restrict__ AO) {
  __shared__ __align__(1024) char sm[32768];
  const int tid = threadIdx.x, wid = tid >> 6, lane = tid & 63;
  const int x = lane & 15, h = lane >> 4;

  // XCD-aware swizzle (1024 % 8 == 0): 4 consecutive bh per XCD (2MB KV < L2)
  const int fid = blockIdx.x;
  const int l = (fid & 7) * 128 + (fid >> 3);
  const int qb = l & 31, bh = l >> 5;

  const size_t base = (size_t)bh * 2048 * 64;   // Q/K [bh][2048][64]; Vt [bh][64][2048]
  const int qr0 = qb * 64 + wid * 16;

  bf16x8 qh[2], ql[2];
  {
    const size_t rq = base + (size_t)(qr0 + x) * 64 + h * 8;
    qh[0] = *(const bf16x8*)&Qh[rq];      qh[1] = *(const bf16x8*)&Qh[rq + 32];
    ql[0] = *(const bf16x8*)&Ql[rq];      ql[1] = *(const bf16x8*)&Ql[rq + 32];
  }

  bf16x8 ones;
  #pragma unroll
  for (int j = 0; j < 8; ++j) ones[j] = (short)0x3F80;   // bf16 1.0

  // staging map (linear dest, pre-swizzled source); 4 loads/lane/tile
  const int dest4 = wid * 1024 + lane * 16;               // within 4KB chunk
  const int lg = dest4 ^ (((dest4 >> 7) & 7) << 4);
  const int srow = lg >> 6, scol = (lg & 63) >> 1;
  const size_t offK = (size_t)srow * 64 + scol;           // + kvb*64 + r*32
  const size_t offV = (size_t)srow * 2048 + scol;         // + kvb + r*32

  const int swk = ((lane >> 1) & 7) << 4;   // read xor for 64B-row tiles
  const int rdo = (x * 64 + h * 16) ^ swk;  // per-lane read base offset

  // bpermute addresses
  const int adrA = (x + 32 * (h & 1)) * 4;  // P redistribution, u<2
  const int adrB = adrA + 64;               // u>=2
  int aQ[4];
  #pragma unroll
  for (int r = 0; r < 4; ++r) aQ[r] = (20 * h + r) * 4;  // row 4h+r, copy h

  float mrun = -INFINITY;                    // per-lane row q = x
  f32x4 o[4] = {};
  f32x4 os = {};                             // row-sums (rows q = 4h+r)

  {  // stage tile 0 -> buf0
    #pragma unroll
    for (int r = 0; r < 2; ++r) {
      gld16(Kb + base + r * 32 + offK, (u16*)(sm + r * 4096 + wid * 1024));
      gld16(Vt + base + r * 32 + offV, (u16*)(sm + 8192 + r * 4096 + wid * 1024));
    }
  }

  for (int kv = 0; kv < 32; ++kv) {
    const int bb = (kv & 1) * 16384;
    __builtin_amdgcn_s_barrier();
    if (kv < 31) {
      const size_t kvb = (size_t)(kv + 1) * 64;
      char* buf = sm + (16384 - bb);
      #pragma unroll
      for (int r = 0; r < 2; ++r) {
        gld16(Kb + base + kvb * 64 + r * 32 + offK,
              (u16*)(buf + r * 4096 + wid * 1024));
        gld16(Vt + base + kvb + r * 32 + offV,
              (u16*)(buf + 8192 + r * 4096 + wid * 1024));
      }
      asm volatile("s_waitcnt vmcnt(4)" ::: "memory");
    } else {
      asm volatile("s_waitcnt vmcnt(0)" ::: "memory");
    }
    __builtin_amdgcn_s_barrier();

    const char* smb = sm + bb + rdo;          // all reads = smb + const imm

    // ---- S^T = K Q^T (Q pre-scaled by 0.125*log2e; Q split, K bf16)
    f32x4 s4[4] = {};
    __builtin_amdgcn_s_setprio(1);
    #pragma unroll
    for (int c = 0; c < 4; ++c)
      #pragma unroll
      for (int ks = 0; ks < 2; ++ks) {
        bf16x8 kb_ = *(const bf16x8*)(smb + ks * 4096 + c * 1024);
        s4[c] = MFMA(kb_, qh[ks], s4[c]);
        s4[c] = MFMA(kb_, ql[ks], s4[c]);
      }
    __builtin_amdgcn_s_setprio(0);

    // ---- per-lane row max: max3 tree + 2-shfl cross reduce
    float m0 = fmaxf(fmaxf(s4[0][0], s4[0][1]), s4[0][2]);
    float m1 = fmaxf(fmaxf(s4[0][3], s4[1][0]), s4[1][1]);
    float m2 = fmaxf(fmaxf(s4[1][2], s4[1][3]), s4[2][0]);
    float m3 = fmaxf(fmaxf(s4[2][1], s4[2][2]), s4[2][3]);
    float m4 = fmaxf(fmaxf(s4[3][0], s4[3][1]), s4[3][2]);
    float m5 = fmaxf(fmaxf(m0, m1), m2);
    float pm = fmaxf(fmaxf(fmaxf(m3, m4), s4[3][3]), m5);
    pm = fmaxf(pm, __shfl_xor(pm, 16, 64));
    pm = fmaxf(pm, __shfl_xor(pm, 32, 64));

    // ---- defer-rescale: only when max grows past THR=7 (P bounded by 128)
    if (__any(pm > mrun + 7.0f)) {
      float mnew = fmaxf(mrun, pm);
      float scl = fexp2(mrun - mnew);
      mrun = mnew;
      float sq[4];
      #pragma unroll
      for (int r = 0; r < 4; ++r)
        sq[r] = u2f((unsigned)__builtin_amdgcn_ds_bpermute(aQ[r], (int)f2u(scl)));
      #pragma unroll
      for (int dfr = 0; dfr < 4; ++dfr)
        #pragma unroll
        for (int r = 0; r < 4; ++r) o[dfr][r] *= sq[r];
      #pragma unroll
      for (int r = 0; r < 4; ++r) os[r] *= sq[r];
    }

    // ---- P = exp2(S - mrun), pack pairs to bf16
    int pk[4][2];
    #pragma unroll
    for (int c = 0; c < 4; ++c)
      #pragma unroll
      for (int m = 0; m < 2; ++m) {
        float p0 = fexp2(s4[c][2 * m] - mrun);
        float p1 = fexp2(s4[c][2 * m + 1] - mrun);
        pk[c][m] = cvtpk(p0, p1);
      }

    // ---- redistribute P into PV A-frags: 16 bpermute + 8 select
    bf16x8 pa[2];
    #pragma unroll
    for (int ks2 = 0; ks2 < 2; ++ks2) {
      union { int w[4]; bf16x8 v; } uu;
      #pragma unroll
      for (int u = 0; u < 4; ++u) {
        const int adr = (u < 2) ? adrA : adrB;
        int r0 = __builtin_amdgcn_ds_bpermute(adr, pk[2 * ks2][u & 1]);
        int r1 = __builtin_amdgcn_ds_bpermute(adr, pk[2 * ks2 + 1][u & 1]);
        uu.w[u] = (h >= 2) ? r1 : r0;
      }
      pa[ks2] = uu.v;
    }

    // ---- PV + MFMA row-sum (ones column)
    __builtin_amdgcn_s_setprio(1);
    #pragma unroll
    for (int ks2 = 0; ks2 < 2; ++ks2) {
      #pragma unroll
      for (int dfr = 0; dfr < 4; ++dfr) {
        bf16x8 vb = *(const bf16x8*)(smb + 8192 + ks2 * 4096 + dfr * 1024);
        o[dfr] = MFMA(pa[ks2], vb, o[dfr]);
      }
      os = MFMA(pa[ks2], ones, os);
    }
    __builtin_amdgcn_s_setprio(0);
  }

  // ---- normalize (os[r] is rowsum for q = 4h+r), bf16-write AO [8192][512]
  const int b = bh >> 3, hd = bh & 7;
  #pragma unroll
  for (int r = 0; r < 4; ++r) {
    const float inv = 1.0f / os[r];
    const int row = qr0 + h * 4 + r;
    #pragma unroll
    for (int dfr = 0; dfr < 4; ++dfr) {
      const int d = dfr * 16 + x;
      AO[((size_t)(b * 2048 + row)) * 512 + hd * 64 + d] = f2bf(o[dfr][r] * inv);
    }
  }
}

// ---------------------------------------------------------------------------
extern "C" void kernel_launch(void* const* d_in, const int* in_sizes, int n_in,
                              void* d_out, int out_size, void* d_ws, size_t ws_size,
                              hipStream_t stream) {
  const float* x    = (const float*)d_in[0];
  const float* wqkv = (const float*)d_in[1];
  const float* wout = (const float*)d_in[2];
  const float* bout = (const float*)d_in[3];
  float* out = (float*)d_out;

  char* w = (char*)d_ws;
  u16* xh  = (u16*)(w + 0);           // 8192x512 bf16 hi
  u16* xl  = (u16*)(w + 8388608);
  u16* wqh = (u16*)(w + 16777216);    // WqkvT [1536][512]
  u16* wql = (u16*)(w + 18350080);
  u16* woh = (u16*)(w + 19922944);    // WoutT [512][512]
  u16* wol = (u16*)(w + 20447232);    // (written, unused)
  u16* Qh  = (u16*)(w + 20971520);    // [32][2048][64]
  u16* Ql  = (u16*)(w + 29360128);
  u16* Kb  = (u16*)(w + 37748736);    // [32][2048][64] bf16
  u16* Vt  = (u16*)(w + 46137344);    // [32][64][2048] bf16
  u16* AO  = (u16*)(w + 54525952);    // [8192][512] bf16; end 62914560

  k_split <<<4096, 256, 0, stream>>>(x, xh, xl, 4194304);
  k_tsplit<<<3072, 256, 0, stream>>>(wqkv, wqh, wql, 1536, 786432);
  k_tsplit<<<1024, 256, 0, stream>>>(wout, woh, wol, 512, 262144);
  k_gemm_qkv<<<dim3(64, 12), 256, 0, stream>>>(xh, xl, wqh, wql,
                                               Qh, Ql, Kb, Vt);
  k_attn<<<1024, 256, 0, stream>>>(Qh, Ql, Kb, Vt, AO);
  k_gemm_out<<<dim3(64, 4), 256, 0, stream>>>(AO, woh, bout, out);
}

// Round 8
// 136.076 us; speedup vs baseline: 1.7108x; 1.0711x over previous
//
#include <hip/hip_runtime.h>
#include <hip/hip_bf16.h>
#include <math.h>
#include <stdint.h>

// ---------------------------------------------------------------------------
// Attention (B=4, N=2048, D=512, H=8, Dh=64) for MI355X.
// Precision plan (threshold 6.48e-3 absolute):
//   x@Wqkv Q/K cols: 3-term split-bf16 MFMA; V cols: 1-term bf16.
//   QK^T: Q split (2-term), K plain bf16.  PV: bf16 P,V.
//   AO plain bf16; out GEMM 1-term bf16.
// R8: 16x16x32 MFMA only (HW-verified layouts), 2 waves x 32 q-rows (two
// q-groups share all K/V fragment reads -> per-q LDS traffic halved vs R5),
// P routed through per-wave swizzled LDS (no cross-lane semantic unknowns).
// ---------------------------------------------------------------------------

typedef unsigned short u16;
typedef __attribute__((ext_vector_type(4))) float f32x4;
typedef __attribute__((ext_vector_type(8))) short bf16x8;   // 8 bf16 = 4 VGPRs
typedef __attribute__((ext_vector_type(4))) short s16x4;

#define AS1 __attribute__((address_space(1)))
#define AS3 __attribute__((address_space(3)))
#define MFMA(a, b, c) __builtin_amdgcn_mfma_f32_16x16x32_bf16(a, b, c, 0, 0, 0)
#define QSCALE 0.180336880f   /* 0.125 * log2(e): logits in log2 domain */

__device__ __forceinline__ u16 f2bf(float f) {
  union { float f; unsigned u; } v; v.f = f;
  unsigned r = v.u + 0x7FFFu + ((v.u >> 16) & 1u);   // RNE
  return (u16)(r >> 16);
}
__device__ __forceinline__ float bf2f(u16 b) {
  union { unsigned u; float f; } v; v.u = ((unsigned)b) << 16; return v.f;
}
__device__ __forceinline__ void splitbf(float x, u16& hi, u16& lo) {
  hi = f2bf(x); lo = f2bf(x - bf2f(hi));
}
__device__ __forceinline__ void gld16(const u16* g, u16* l) {
  __builtin_amdgcn_global_load_lds((const AS1 void*)g, (AS3 void*)l, 16, 0, 0);
}
__device__ __forceinline__ float u2f(unsigned u) {
  union { unsigned u; float f; } v; v.u = u; return v.f;
}
__device__ __forceinline__ unsigned f2u(float f) {
  union { float f; unsigned u; } v; v.f = f; return v.u;
}
__device__ __forceinline__ int cvtpk(float lo, float hi) {
  int r; asm("v_cvt_pk_bf16_f32 %0, %1, %2" : "=v"(r) : "v"(lo), "v"(hi));
  return r;
}
__device__ __forceinline__ float fexp2(float x) {
  float r; asm("v_exp_f32 %0, %1" : "=v"(r) : "v"(x));
  return r;
}

// ---------------- prep kernels -------------------------------------------
__global__ void k_split(const float* __restrict__ s, u16* __restrict__ h,
                        u16* __restrict__ l, int n) {
  int i = (blockIdx.x * 256 + threadIdx.x) * 4;
  if (i < n) {
    f32x4 v = *(const f32x4*)&s[i];
    s16x4 hh, ll;
    #pragma unroll
    for (int j = 0; j < 4; ++j) {
      u16 a, b; splitbf(v[j], a, b);
      hh[j] = (short)a; ll[j] = (short)b;
    }
    *(s16x4*)&h[i] = hh;
    *(s16x4*)&l[i] = ll;
  }
}

// src [512][N] row-major -> dst [N][512] (transposed), split hi/lo
__global__ void k_tsplit(const float* __restrict__ s, u16* __restrict__ h,
                         u16* __restrict__ l, int N, int total) {
  int i = blockIdx.x * 256 + threadIdx.x;          // i = n*512 + k
  if (i < total) {
    int n = i >> 9, k = i & 511;
    u16 a, b; splitbf(s[(size_t)k * N + n], a, b);
    h[i] = a; l[i] = b;
  }
}

// ---------------- shared GEMM core: C[128x128] tile, K=512, BK=32 ----------
// FAST: 1-term bf16 (hi only).  !FAST: 3-term split.
template <bool FAST>
__device__ __forceinline__ void gemm_core(
    const u16* __restrict__ Ah, const u16* __restrict__ Al,
    const u16* __restrict__ Bh, const u16* __restrict__ Bl,
    char* sm, int rowA, int rowB, int tid, f32x4 (&acc)[4][4]) {
  const int wid = tid >> 6, lane = tid & 63;
  const int x = lane & 15, h = lane >> 4;
  const int wr = wid >> 1, wc = wid & 1;
  const int d0 = wid * 1024 + lane * 16;
  const int lg0 = d0 ^ (((d0 >> 7) & 7) << 4);
  const int srow = lg0 >> 6;
  const int scol = (lg0 & 63) >> 1;
  const int swk = ((lane >> 1) & 7) << 4;
  const char* smA = sm + (((wr * 64 + x) * 64 + h * 16) ^ swk);
  const char* smB = sm + (((wc * 64 + x) * 64 + h * 16) ^ swk);

  for (int kt = 0; kt < 16; ++kt) {
    const int kofs = kt * 32;
    __syncthreads();
    #pragma unroll
    for (int r = 0; r < 2; ++r) {
      const int row  = r * 64 + srow;
      const int ldst = r * 4096 + wid * 1024;
      const size_t ga = (size_t)(rowA + row) * 512 + kofs + scol;
      const size_t gb = (size_t)(rowB + row) * 512 + kofs + scol;
      gld16(Ah + ga, (u16*)(sm + ldst));
      gld16(Bh + gb, (u16*)(sm + 16384 + ldst));
      if (!FAST) {
        gld16(Al + ga, (u16*)(sm + 8192 + ldst));
        gld16(Bl + gb, (u16*)(sm + 24576 + ldst));
      }
    }
    __syncthreads();
    bf16x8 a_h[4], a_l[4], b_h[4], b_l[4];
    #pragma unroll
    for (int i = 0; i < 4; ++i) {
      a_h[i] = *(const bf16x8*)(smA + i * 1024);
      if (!FAST) a_l[i] = *(const bf16x8*)(smA + 8192 + i * 1024);
    }
    #pragma unroll
    for (int j = 0; j < 4; ++j) {
      b_h[j] = *(const bf16x8*)(smB + 16384 + j * 1024);
      if (!FAST) b_l[j] = *(const bf16x8*)(smB + 24576 + j * 1024);
    }
    __builtin_amdgcn_s_setprio(1);
    #pragma unroll
    for (int i = 0; i < 4; ++i)
      #pragma unroll
      for (int j = 0; j < 4; ++j) {
        acc[i][j] = MFMA(a_h[i], b_h[j], acc[i][j]);
        if (!FAST) {
          acc[i][j] = MFMA(a_h[i], b_l[j], acc[i][j]);
          acc[i][j] = MFMA(a_l[i], b_h[j], acc[i][j]);
        }
      }
    __builtin_amdgcn_s_setprio(0);
  }
}

// ---------------- QKV projection -------------------------------------------
// n<512: Q (xQSCALE, split -> Qh/Ql [bh][n][64]); 512..1023: K -> bf16 Kb;
// >=1024: V -> Vt [bh][64][2048] bf16 (1-term fast path).
__global__ __launch_bounds__(256) void k_gemm_qkv(
    const u16* __restrict__ Ah, const u16* __restrict__ Al,
    const u16* __restrict__ Bh, const u16* __restrict__ Bl,
    u16* __restrict__ Qh, u16* __restrict__ Ql,
    u16* __restrict__ Kb, u16* __restrict__ Vt) {
  __shared__ __align__(1024) char sm[32768];
  const int tid = threadIdx.x, lane = tid & 63, wid = tid >> 6;
  const int x = lane & 15, h = lane >> 4;
  const int wr = wid >> 1, wc = wid & 1;
  const int rowA = blockIdx.x * 128, rowB = blockIdx.y * 128;
  f32x4 acc[4][4] = {};
  if (rowB >= 1024)
    gemm_core<true>(Ah, Al, Bh, Bl, sm, rowA, rowB, tid, acc);
  else
    gemm_core<false>(Ah, Al, Bh, Bl, sm, rowA, rowB, tid, acc);

  #pragma unroll
  for (int i = 0; i < 4; ++i)
    #pragma unroll
    for (int j = 0; j < 4; ++j) {
      const int n = rowB + wc * 64 + j * 16 + x;
      const int which = n >> 9;
      const int hh = (n >> 6) & 7, d = n & 63;
      const int m0 = rowA + wr * 64 + i * 16 + h * 4;
      const int b = m0 >> 11, is0 = m0 & 2047;
      if (which == 0) {
        #pragma unroll
        for (int r = 0; r < 4; ++r) {
          u16 hi, lo; splitbf(acc[i][j][r] * QSCALE, hi, lo);
          const size_t idx = ((size_t)((b * 8 + hh) * 2048 + is0 + r)) * 64 + d;
          Qh[idx] = hi; Ql[idx] = lo;
        }
      } else if (which == 1) {
        #pragma unroll
        for (int r = 0; r < 4; ++r) {
          const size_t idx = ((size_t)((b * 8 + hh) * 2048 + is0 + r)) * 64 + d;
          Kb[idx] = f2bf(acc[i][j][r]);
        }
      } else {
        s16x4 vv;
        #pragma unroll
        for (int r = 0; r < 4; ++r) vv[r] = (short)f2bf(acc[i][j][r]);
        *(s16x4*)&Vt[((size_t)((b * 8 + hh) * 64 + d)) * 2048 + is0] = vv;
      }
    }
}

// ---------------- output projection (1-term bf16) --------------------------
__global__ __launch_bounds__(256) void k_gemm_out(
    const u16* __restrict__ Ah, const u16* __restrict__ Bh,
    const float* __restrict__ bias, float* __restrict__ out) {
  __shared__ __align__(1024) char sm[32768];
  const int tid = threadIdx.x, lane = tid & 63, wid = tid >> 6;
  const int x = lane & 15, h = lane >> 4;
  const int wr = wid >> 1, wc = wid & 1;
  const int rowA = blockIdx.x * 128, rowB = blockIdx.y * 128;
  f32x4 acc[4][4] = {};
  gemm_core<true>(Ah, Ah, Bh, Bh, sm, rowA, rowB, tid, acc);

  #pragma unroll
  for (int i = 0; i < 4; ++i)
    #pragma unroll
    for (int j = 0; j < 4; ++j) {
      const int n = rowB + wc * 64 + j * 16 + x;
      #pragma unroll
      for (int r = 0; r < 4; ++r) {
        const int m = rowA + wr * 64 + i * 16 + h * 4 + r;
        out[(size_t)m * 512 + n] = acc[i][j][r] + bias[n];
      }
    }
}

// ---------------- flash attention (16x16 MFMA, 32 q/wave) -------------------
// Grid 1024 blocks (XCD-swizzled), 128 thr = 2 waves x 32 q-rows (QBLK=64).
// KV tile 64.  Per wave: 2 q-groups of 16 share every K/V fragment read.
// Swapped QK^T per group: lane (x,h) holds S^T[k=c*16+h*4+r][q=g*16+x].
// P -> per-wave LDS [32 q][64 kv] (128B rows, ^((q&7)<<4) swizzle), read
// back as PV A-frags.  Row-sum via MFMA(P, ones).  Defer-rescale THR=7.
// LDS: KV dbuf 2x16KB {K0,K1,V0,V1 4KB chunks, 64B rows, XOR involution} +
// per-wave P 4KB = 40KB.
__global__ __launch_bounds__(128, 2) void k_attn(
    const u16* __restrict__ Qh, const u16* __restrict__ Ql,
    const u16* __restrict__ Kb, const u16* __restrict__ Vt,
    u16* __restrict__ AO) {
  __shared__ __align__(1024) char sm[40960];
  const int tid = threadIdx.x, wid = tid >> 6, lane = tid & 63;
  const int x = lane & 15, h = lane >> 4;

  // XCD-aware swizzle (1024 % 8 == 0): 4 consecutive bh per XCD
  const int fid = blockIdx.x;
  const int l = (fid & 7) * 128 + (fid >> 3);
  const int qb = l & 31, bh = l >> 5;

  const size_t base = (size_t)bh * 2048 * 64;   // Q/K [bh][2048][64]; Vt [bh][64][2048]
  const int qr0 = qb * 64 + wid * 32;

  // Q B-frags per group g: lane (x,h) holds Q[qr0+g*16+x][d=ks*32+h*8+j]
  bf16x8 qh[2][2], ql[2][2];
  #pragma unroll
  for (int g = 0; g < 2; ++g) {
    const size_t rq = base + (size_t)(qr0 + g * 16 + x) * 64 + h * 8;
    #pragma unroll
    for (int ks = 0; ks < 2; ++ks) {
      qh[g][ks] = *(const bf16x8*)&Qh[rq + ks * 32];
      ql[g][ks] = *(const bf16x8*)&Ql[rq + ks * 32];
    }
  }

  bf16x8 ones;
  #pragma unroll
  for (int j = 0; j < 8; ++j) ones[j] = (short)0x3F80;   // bf16 1.0

  // staging map (128 thr): dest byte db = r*2048 + tid*16 per 4KB chunk
  int srow[2], scb[2];
  #pragma unroll
  for (int r = 0; r < 2; ++r) {
    const int db = r * 2048 + tid * 16;
    const int lg = db ^ (((db >> 7) & 7) << 4);
    srow[r] = lg >> 6;
    scb[r] = (lg & 63) >> 1;
  }

  const int swk = ((lane >> 1) & 7) << 4;   // read xor for 64B-row tiles
  const int rdo = (x * 64 + h * 16) ^ swk;  // per-lane K/V read base offset
  char* const pb = sm + 32768 + wid * 4096; // per-wave P buffer
  const int pxor = (x & 7) << 4;            // P row swizzle
  const int prow = x * 128;                 // P row base (g adds 2048)

  float mrun[2] = {-INFINITY, -INFINITY};
  f32x4 o[2][4] = {};
  f32x4 os[2] = {};

  {  // stage tile 0 -> buf0
    #pragma unroll
    for (int r = 0; r < 2; ++r) {
      const size_t kR = base + (size_t)srow[r] * 64 + scb[r];
      const size_t vR = base + (size_t)srow[r] * 2048 + scb[r];
      const int db = r * 2048 + tid * 16;
      gld16(Kb + kR,      (u16*)(sm + db));
      gld16(Kb + kR + 32, (u16*)(sm + 4096 + db));
      gld16(Vt + vR,      (u16*)(sm + 8192 + db));
      gld16(Vt + vR + 32, (u16*)(sm + 12288 + db));
    }
  }

  for (int kv = 0; kv < 32; ++kv) {
    const int bb = (kv & 1) * 16384;
    __builtin_amdgcn_s_barrier();
    if (kv < 31) {
      const size_t kvb = (size_t)(kv + 1) * 64;
      char* buf = sm + (16384 - bb);
      #pragma unroll
      for (int r = 0; r < 2; ++r) {
        const size_t kR = base + (kvb + srow[r]) * 64 + scb[r];
        const size_t vR = base + (size_t)srow[r] * 2048 + kvb + scb[r];
        const int db = r * 2048 + tid * 16;
        gld16(Kb + kR,      (u16*)(buf + db));
        gld16(Kb + kR + 32, (u16*)(buf + 4096 + db));
        gld16(Vt + vR,      (u16*)(buf + 8192 + db));
        gld16(Vt + vR + 32, (u16*)(buf + 12288 + db));
      }
      asm volatile("s_waitcnt vmcnt(8)" ::: "memory");
    } else {
      asm volatile("s_waitcnt vmcnt(0)" ::: "memory");
    }
    __builtin_amdgcn_s_barrier();

    const char* smb = sm + bb + rdo;

    // ---- S^T = K Q^T (Q pre-scaled by 0.125*log2e; Q split 2-term)
    f32x4 s[2][4] = {};
    __builtin_amdgcn_s_setprio(1);
    #pragma unroll
    for (int c = 0; c < 4; ++c)
      #pragma unroll
      for (int ks = 0; ks < 2; ++ks) {
        bf16x8 kb_ = *(const bf16x8*)(smb + ks * 4096 + c * 1024);
        s[0][c] = MFMA(kb_, qh[0][ks], s[0][c]);
        s[0][c] = MFMA(kb_, ql[0][ks], s[0][c]);
        s[1][c] = MFMA(kb_, qh[1][ks], s[1][c]);
        s[1][c] = MFMA(kb_, ql[1][ks], s[1][c]);
      }
    __builtin_amdgcn_s_setprio(0);

    // ---- per-group row max (16 local) + 2-shfl cross reduce over h-lanes
    float pm[2];
    #pragma unroll
    for (int g = 0; g < 2; ++g) {
      float m0 = fmaxf(fmaxf(s[g][0][0], s[g][0][1]), s[g][0][2]);
      float m1 = fmaxf(fmaxf(s[g][0][3], s[g][1][0]), s[g][1][1]);
      float m2 = fmaxf(fmaxf(s[g][1][2], s[g][1][3]), s[g][2][0]);
      float m3 = fmaxf(fmaxf(s[g][2][1], s[g][2][2]), s[g][2][3]);
      float m4 = fmaxf(fmaxf(s[g][3][0], s[g][3][1]), s[g][3][2]);
      float m5 = fmaxf(fmaxf(m0, m1), m2);
      float p  = fmaxf(fmaxf(fmaxf(m3, m4), s[g][3][3]), m5);
      p = fmaxf(p, __shfl_xor(p, 16, 64));
      p = fmaxf(p, __shfl_xor(p, 32, 64));
      pm[g] = p;
    }

    // ---- defer-rescale (THR=7 in log2; P bounded by 128)
    if (__any((pm[0] > mrun[0] + 7.0f) || (pm[1] > mrun[1] + 7.0f))) {
      #pragma unroll
      for (int g = 0; g < 2; ++g) {
        float mnew = fmaxf(mrun[g], pm[g]);
        float scl = fexp2(mrun[g] - mnew);
        mrun[g] = mnew;
        #pragma unroll
        for (int r = 0; r < 4; ++r) {
          float sq = u2f((unsigned)__builtin_amdgcn_ds_bpermute(
              (20 * h + r) * 4, (int)f2u(scl)));
          os[g][r] *= sq;
          #pragma unroll
          for (int dg = 0; dg < 4; ++dg) o[g][dg][r] *= sq;
        }
      }
    }

    // ---- P = exp2(S - mrun) -> bf16 pairs -> per-wave LDS [32q][64kv]
    #pragma unroll
    for (int g = 0; g < 2; ++g)
      #pragma unroll
      for (int c = 0; c < 4; ++c) {
        int w0 = cvtpk(fexp2(s[g][c][0] - mrun[g]),
                       fexp2(s[g][c][1] - mrun[g]));
        int w1 = cvtpk(fexp2(s[g][c][2] - mrun[g]),
                       fexp2(s[g][c][3] - mrun[g]));
        int* dst = (int*)(pb + g * 2048 + prow + ((c * 32 + h * 8) ^ pxor));
        dst[0] = w0; dst[1] = w1;
      }

    // ---- PV + row-sum (P A-frags re-read from LDS; same-wave, no barrier)
    __builtin_amdgcn_s_setprio(1);
    #pragma unroll
    for (int ch = 0; ch < 2; ++ch) {
      bf16x8 pa0 = *(const bf16x8*)(pb + prow +
                                    ((ch * 64 + h * 16) ^ pxor));
      bf16x8 pa1 = *(const bf16x8*)(pb + 2048 + prow +
                                    ((ch * 64 + h * 16) ^ pxor));
      os[0] = MFMA(pa0, ones, os[0]);
      os[1] = MFMA(pa1, ones, os[1]);
      #pragma unroll
      for (int dg = 0; dg < 4; ++dg) {
        bf16x8 vb = *(const bf16x8*)(smb + 8192 + ch * 4096 + dg * 1024);
        o[0][dg] = MFMA(pa0, vb, o[0][dg]);
        o[1][dg] = MFMA(pa1, vb, o[1][dg]);
      }
    }
    __builtin_amdgcn_s_setprio(0);
  }

  // ---- normalize (os[g][r] = rowsum for q = g*16+h*4+r), write AO bf16
  const int b_ = bh >> 3, head = bh & 7;
  #pragma unroll
  for (int g = 0; g < 2; ++g)
    #pragma unroll
    for (int r = 0; r < 4; ++r) {
      const float inv = 1.0f / os[g][r];
      const int row = qr0 + g * 16 + h * 4 + r;
      #pragma unroll
      for (int dg = 0; dg < 4; ++dg) {
        AO[((size_t)(b_ * 2048 + row)) * 512 + head * 64 + dg * 16 + x] =
            f2bf(o[g][dg][r] * inv);
      }
    }
}

// ---------------------------------------------------------------------------
extern "C" void kernel_launch(void* const* d_in, const int* in_sizes, int n_in,
                              void* d_out, int out_size, void* d_ws, size_t ws_size,
                              hipStream_t stream) {
  const float* x    = (const float*)d_in[0];
  const float* wqkv = (const float*)d_in[1];
  const float* wout = (const float*)d_in[2];
  const float* bout = (const float*)d_in[3];
  float* out = (float*)d_out;

  char* w = (char*)d_ws;
  u16* xh  = (u16*)(w + 0);           // 8192x512 bf16 hi
  u16* xl  = (u16*)(w + 8388608);
  u16* wqh = (u16*)(w + 16777216);    // WqkvT [1536][512]
  u16* wql = (u16*)(w + 18350080);
  u16* woh = (u16*)(w + 19922944);    // WoutT [512][512]
  u16* wol = (u16*)(w + 20447232);    // (written, unused)
  u16* Qh  = (u16*)(w + 20971520);    // [32][2048][64]
  u16* Ql  = (u16*)(w + 29360128);
  u16* Kb  = (u16*)(w + 37748736);    // [32][2048][64] bf16
  u16* Vt  = (u16*)(w + 46137344);    // [32][64][2048] bf16
  u16* AO  = (u16*)(w + 54525952);    // [8192][512] bf16; end 62914560

  k_split <<<4096, 256, 0, stream>>>(x, xh, xl, 4194304);
  k_tsplit<<<3072, 256, 0, stream>>>(wqkv, wqh, wql, 1536, 786432);
  k_tsplit<<<1024, 256, 0, stream>>>(wout, woh, wol, 512, 262144);
  k_gemm_qkv<<<dim3(64, 12), 256, 0, stream>>>(xh, xl, wqh, wql,
                                               Qh, Ql, Kb, Vt);
  k_attn<<<1024, 128, 0, stream>>>(Qh, Ql, Kb, Vt, AO);
  k_gemm_out<<<dim3(64, 4), 256, 0, stream>>>(AO, woh, bout, out);
}

// Round 9
// 112.115 us; speedup vs baseline: 2.0765x; 1.2137x over previous
//
#include <hip/hip_runtime.h>
#include <hip/hip_bf16.h>
#include <math.h>
#include <stdint.h>

// ---------------------------------------------------------------------------
// Attention (B=4, N=2048, D=512, H=8, Dh=64) for MI355X.
// Precision plan (threshold 6.48e-3 absolute; measured floor 1.95e-3):
//   x@Wqkv Q/K cols: 2-term (ah*bh + ah*bl = exact-x_hat*W); V cols 1-term.
//   QK^T: plain bf16 both sides.  PV: bf16 P,V.  AO bf16; out GEMM 1-term.
// R9: spend measured precision slack -> 1-term QK^T (attn MFMA -31%),
// 2-term QKV GEMM (Q/K region MFMA -33%, no x-lo split), cast-only k_split.
// ---------------------------------------------------------------------------

typedef unsigned short u16;
typedef __attribute__((ext_vector_type(4))) float f32x4;
typedef __attribute__((ext_vector_type(8))) short bf16x8;   // 8 bf16 = 4 VGPRs
typedef __attribute__((ext_vector_type(4))) short s16x4;

#define AS1 __attribute__((address_space(1)))
#define AS3 __attribute__((address_space(3)))
#define MFMA(a, b, c) __builtin_amdgcn_mfma_f32_16x16x32_bf16(a, b, c, 0, 0, 0)
#define QSCALE 0.180336880f   /* 0.125 * log2(e): logits in log2 domain */

__device__ __forceinline__ u16 f2bf(float f) {
  union { float f; unsigned u; } v; v.f = f;
  unsigned r = v.u + 0x7FFFu + ((v.u >> 16) & 1u);   // RNE
  return (u16)(r >> 16);
}
__device__ __forceinline__ float bf2f(u16 b) {
  union { unsigned u; float f; } v; v.u = ((unsigned)b) << 16; return v.f;
}
__device__ __forceinline__ void splitbf(float x, u16& hi, u16& lo) {
  hi = f2bf(x); lo = f2bf(x - bf2f(hi));
}
__device__ __forceinline__ void gld16(const u16* g, u16* l) {
  __builtin_amdgcn_global_load_lds((const AS1 void*)g, (AS3 void*)l, 16, 0, 0);
}
__device__ __forceinline__ float u2f(unsigned u) {
  union { unsigned u; float f; } v; v.u = u; return v.f;
}
__device__ __forceinline__ unsigned f2u(float f) {
  union { float f; unsigned u; } v; v.f = f; return v.u;
}
__device__ __forceinline__ int cvtpk(float lo, float hi) {
  int r; asm("v_cvt_pk_bf16_f32 %0, %1, %2" : "=v"(r) : "v"(lo), "v"(hi));
  return r;
}
__device__ __forceinline__ float fexp2(float x) {
  float r; asm("v_exp_f32 %0, %1" : "=v"(r) : "v"(x));
  return r;
}

// ---------------- prep kernels -------------------------------------------
// plain fp32 -> bf16 cast (A-side of 2-term GEMM needs hi only)
__global__ void k_cast(const float* __restrict__ s, u16* __restrict__ h, int n) {
  int i = (blockIdx.x * 256 + threadIdx.x) * 4;
  if (i < n) {
    f32x4 v = *(const f32x4*)&s[i];
    s16x4 hh;
    #pragma unroll
    for (int j = 0; j < 4; ++j) hh[j] = (short)f2bf(v[j]);
    *(s16x4*)&h[i] = hh;
  }
}

// src [512][N] row-major -> dst [N][512] (transposed), split hi/lo
__global__ void k_tsplit(const float* __restrict__ s, u16* __restrict__ h,
                         u16* __restrict__ l, int N, int total) {
  int i = blockIdx.x * 256 + threadIdx.x;          // i = n*512 + k
  if (i < total) {
    int n = i >> 9, k = i & 511;
    u16 a, b; splitbf(s[(size_t)k * N + n], a, b);
    h[i] = a; l[i] = b;
  }
}

// ---------------- shared GEMM core: C[128x128] tile, K=512, BK=32 ----------
// TERMS=1: ah*bh.  TERMS=2: ah*bh + ah*bl (exact-x_hat * W).
template <int TERMS>
__device__ __forceinline__ void gemm_core(
    const u16* __restrict__ Ah,
    const u16* __restrict__ Bh, const u16* __restrict__ Bl,
    char* sm, int rowA, int rowB, int tid, f32x4 (&acc)[4][4]) {
  const int wid = tid >> 6, lane = tid & 63;
  const int x = lane & 15, h = lane >> 4;
  const int wr = wid >> 1, wc = wid & 1;
  const int d0 = wid * 1024 + lane * 16;
  const int lg0 = d0 ^ (((d0 >> 7) & 7) << 4);
  const int srow = lg0 >> 6;
  const int scol = (lg0 & 63) >> 1;
  const int swk = ((lane >> 1) & 7) << 4;
  const char* smA = sm + (((wr * 64 + x) * 64 + h * 16) ^ swk);
  const char* smB = sm + (((wc * 64 + x) * 64 + h * 16) ^ swk);

  for (int kt = 0; kt < 16; ++kt) {
    const int kofs = kt * 32;
    __syncthreads();
    #pragma unroll
    for (int r = 0; r < 2; ++r) {
      const int row  = r * 64 + srow;
      const int ldst = r * 4096 + wid * 1024;
      const size_t ga = (size_t)(rowA + row) * 512 + kofs + scol;
      const size_t gb = (size_t)(rowB + row) * 512 + kofs + scol;
      gld16(Ah + ga, (u16*)(sm + ldst));
      gld16(Bh + gb, (u16*)(sm + 16384 + ldst));
      if (TERMS == 2) gld16(Bl + gb, (u16*)(sm + 24576 + ldst));
    }
    __syncthreads();
    bf16x8 a_h[4], b_h[4], b_l[4];
    #pragma unroll
    for (int i = 0; i < 4; ++i)
      a_h[i] = *(const bf16x8*)(smA + i * 1024);
    #pragma unroll
    for (int j = 0; j < 4; ++j) {
      b_h[j] = *(const bf16x8*)(smB + 16384 + j * 1024);
      if (TERMS == 2) b_l[j] = *(const bf16x8*)(smB + 24576 + j * 1024);
    }
    __builtin_amdgcn_s_setprio(1);
    #pragma unroll
    for (int i = 0; i < 4; ++i)
      #pragma unroll
      for (int j = 0; j < 4; ++j) {
        acc[i][j] = MFMA(a_h[i], b_h[j], acc[i][j]);
        if (TERMS == 2) acc[i][j] = MFMA(a_h[i], b_l[j], acc[i][j]);
      }
    __builtin_amdgcn_s_setprio(0);
  }
}

// ---------------- QKV projection -------------------------------------------
// n<512: Q (xQSCALE -> bf16 Qb [bh][n][64]); 512..1023: K -> bf16 Kb;
// >=1024: V -> Vt [bh][64][2048] bf16 (1-term fast path).
__global__ __launch_bounds__(256) void k_gemm_qkv(
    const u16* __restrict__ Ah,
    const u16* __restrict__ Bh, const u16* __restrict__ Bl,
    u16* __restrict__ Qb, u16* __restrict__ Kb, u16* __restrict__ Vt) {
  __shared__ __align__(1024) char sm[32768];
  const int tid = threadIdx.x, lane = tid & 63, wid = tid >> 6;
  const int x = lane & 15, h = lane >> 4;
  const int wr = wid >> 1, wc = wid & 1;
  const int rowA = blockIdx.x * 128, rowB = blockIdx.y * 128;
  f32x4 acc[4][4] = {};
  if (rowB >= 1024)
    gemm_core<1>(Ah, Bh, Bl, sm, rowA, rowB, tid, acc);
  else
    gemm_core<2>(Ah, Bh, Bl, sm, rowA, rowB, tid, acc);

  #pragma unroll
  for (int i = 0; i < 4; ++i)
    #pragma unroll
    for (int j = 0; j < 4; ++j) {
      const int n = rowB + wc * 64 + j * 16 + x;
      const int which = n >> 9;
      const int hh = (n >> 6) & 7, d = n & 63;
      const int m0 = rowA + wr * 64 + i * 16 + h * 4;
      const int b = m0 >> 11, is0 = m0 & 2047;
      if (which == 0) {
        #pragma unroll
        for (int r = 0; r < 4; ++r) {
          const size_t idx = ((size_t)((b * 8 + hh) * 2048 + is0 + r)) * 64 + d;
          Qb[idx] = f2bf(acc[i][j][r] * QSCALE);
        }
      } else if (which == 1) {
        #pragma unroll
        for (int r = 0; r < 4; ++r) {
          const size_t idx = ((size_t)((b * 8 + hh) * 2048 + is0 + r)) * 64 + d;
          Kb[idx] = f2bf(acc[i][j][r]);
        }
      } else {
        s16x4 vv;
        #pragma unroll
        for (int r = 0; r < 4; ++r) vv[r] = (short)f2bf(acc[i][j][r]);
        *(s16x4*)&Vt[((size_t)((b * 8 + hh) * 64 + d)) * 2048 + is0] = vv;
      }
    }
}

// ---------------- output projection (1-term bf16) --------------------------
__global__ __launch_bounds__(256) void k_gemm_out(
    const u16* __restrict__ Ah, const u16* __restrict__ Bh,
    const float* __restrict__ bias, float* __restrict__ out) {
  __shared__ __align__(1024) char sm[32768];
  const int tid = threadIdx.x, lane = tid & 63, wid = tid >> 6;
  const int x = lane & 15, h = lane >> 4;
  const int wr = wid >> 1, wc = wid & 1;
  const int rowA = blockIdx.x * 128, rowB = blockIdx.y * 128;
  f32x4 acc[4][4] = {};
  gemm_core<1>(Ah, Bh, Bh, sm, rowA, rowB, tid, acc);

  #pragma unroll
  for (int i = 0; i < 4; ++i)
    #pragma unroll
    for (int j = 0; j < 4; ++j) {
      const int n = rowB + wc * 64 + j * 16 + x;
      #pragma unroll
      for (int r = 0; r < 4; ++r) {
        const int m = rowA + wr * 64 + i * 16 + h * 4 + r;
        out[(size_t)m * 512 + n] = acc[i][j][r] + bias[n];
      }
    }
}

// ---------------- flash attention (16x16 MFMA, 32 q/wave) -------------------
// Grid 1024 blocks (XCD-swizzled), 128 thr = 2 waves x 32 q-rows (QBLK=64).
// KV tile 64.  Per wave: 2 q-groups of 16 share every K/V fragment read.
// Swapped QK^T per group (1-term bf16): lane (x,h) holds
// S^T[k=c*16+h*4+r][q=g*16+x].  P -> per-wave LDS [32 q][64 kv] (128B rows,
// ^((q&7)<<4) swizzle), read back as PV A-frags.  Row-sum via MFMA(P, ones).
// Defer-rescale THR=7.  LDS: KV dbuf 2x16KB + per-wave P 4KB = 40KB.
__global__ __launch_bounds__(128, 2) void k_attn(
    const u16* __restrict__ Qb,
    const u16* __restrict__ Kb, const u16* __restrict__ Vt,
    u16* __restrict__ AO) {
  __shared__ __align__(1024) char sm[40960];
  const int tid = threadIdx.x, wid = tid >> 6, lane = tid & 63;
  const int x = lane & 15, h = lane >> 4;

  // XCD-aware swizzle (1024 % 8 == 0): 4 consecutive bh per XCD
  const int fid = blockIdx.x;
  const int l = (fid & 7) * 128 + (fid >> 3);
  const int qb = l & 31, bh = l >> 5;

  const size_t base = (size_t)bh * 2048 * 64;   // Q/K [bh][2048][64]; Vt [bh][64][2048]
  const int qr0 = qb * 64 + wid * 32;

  // Q B-frags per group g: lane (x,h) holds Q[qr0+g*16+x][d=ks*32+h*8+j]
  bf16x8 qh[2][2];
  #pragma unroll
  for (int g = 0; g < 2; ++g) {
    const size_t rq = base + (size_t)(qr0 + g * 16 + x) * 64 + h * 8;
    #pragma unroll
    for (int ks = 0; ks < 2; ++ks)
      qh[g][ks] = *(const bf16x8*)&Qb[rq + ks * 32];
  }

  bf16x8 ones;
  #pragma unroll
  for (int j = 0; j < 8; ++j) ones[j] = (short)0x3F80;   // bf16 1.0

  // staging map (128 thr): dest byte db = r*2048 + tid*16 per 4KB chunk
  int srow[2], scb[2];
  #pragma unroll
  for (int r = 0; r < 2; ++r) {
    const int db = r * 2048 + tid * 16;
    const int lg = db ^ (((db >> 7) & 7) << 4);
    srow[r] = lg >> 6;
    scb[r] = (lg & 63) >> 1;
  }

  const int swk = ((lane >> 1) & 7) << 4;   // read xor for 64B-row tiles
  const int rdo = (x * 64 + h * 16) ^ swk;  // per-lane K/V read base offset
  char* const pb = sm + 32768 + wid * 4096; // per-wave P buffer
  const int pxor = (x & 7) << 4;            // P row swizzle
  const int prow = x * 128;                 // P row base (g adds 2048)

  float mrun[2] = {-INFINITY, -INFINITY};
  f32x4 o[2][4] = {};
  f32x4 os[2] = {};

  {  // stage tile 0 -> buf0
    #pragma unroll
    for (int r = 0; r < 2; ++r) {
      const size_t kR = base + (size_t)srow[r] * 64 + scb[r];
      const size_t vR = base + (size_t)srow[r] * 2048 + scb[r];
      const int db = r * 2048 + tid * 16;
      gld16(Kb + kR,      (u16*)(sm + db));
      gld16(Kb + kR + 32, (u16*)(sm + 4096 + db));
      gld16(Vt + vR,      (u16*)(sm + 8192 + db));
      gld16(Vt + vR + 32, (u16*)(sm + 12288 + db));
    }
  }

  for (int kv = 0; kv < 32; ++kv) {
    const int bb = (kv & 1) * 16384;
    __builtin_amdgcn_s_barrier();
    if (kv < 31) {
      const size_t kvb = (size_t)(kv + 1) * 64;
      char* buf = sm + (16384 - bb);
      #pragma unroll
      for (int r = 0; r < 2; ++r) {
        const size_t kR = base + (kvb + srow[r]) * 64 + scb[r];
        const size_t vR = base + (size_t)srow[r] * 2048 + kvb + scb[r];
        const int db = r * 2048 + tid * 16;
        gld16(Kb + kR,      (u16*)(buf + db));
        gld16(Kb + kR + 32, (u16*)(buf + 4096 + db));
        gld16(Vt + vR,      (u16*)(buf + 8192 + db));
        gld16(Vt + vR + 32, (u16*)(buf + 12288 + db));
      }
      asm volatile("s_waitcnt vmcnt(8)" ::: "memory");
    } else {
      asm volatile("s_waitcnt vmcnt(0)" ::: "memory");
    }
    __builtin_amdgcn_s_barrier();

    const char* smb = sm + bb + rdo;

    // ---- S^T = K Q^T (1-term bf16; Q pre-scaled by 0.125*log2e)
    f32x4 s[2][4] = {};
    __builtin_amdgcn_s_setprio(1);
    #pragma unroll
    for (int c = 0; c < 4; ++c)
      #pragma unroll
      for (int ks = 0; ks < 2; ++ks) {
        bf16x8 kb_ = *(const bf16x8*)(smb + ks * 4096 + c * 1024);
        s[0][c] = MFMA(kb_, qh[0][ks], s[0][c]);
        s[1][c] = MFMA(kb_, qh[1][ks], s[1][c]);
      }
    __builtin_amdgcn_s_setprio(0);

    // ---- per-group row max (16 local) + 2-shfl cross reduce over h-lanes
    float pm[2];
    #pragma unroll
    for (int g = 0; g < 2; ++g) {
      float m0 = fmaxf(fmaxf(s[g][0][0], s[g][0][1]), s[g][0][2]);
      float m1 = fmaxf(fmaxf(s[g][0][3], s[g][1][0]), s[g][1][1]);
      float m2 = fmaxf(fmaxf(s[g][1][2], s[g][1][3]), s[g][2][0]);
      float m3 = fmaxf(fmaxf(s[g][2][1], s[g][2][2]), s[g][2][3]);
      float m4 = fmaxf(fmaxf(s[g][3][0], s[g][3][1]), s[g][3][2]);
      float m5 = fmaxf(fmaxf(m0, m1), m2);
      float p  = fmaxf(fmaxf(fmaxf(m3, m4), s[g][3][3]), m5);
      p = fmaxf(p, __shfl_xor(p, 16, 64));
      p = fmaxf(p, __shfl_xor(p, 32, 64));
      pm[g] = p;
    }

    // ---- defer-rescale (THR=7 in log2; P bounded by 128)
    if (__any((pm[0] > mrun[0] + 7.0f) || (pm[1] > mrun[1] + 7.0f))) {
      #pragma unroll
      for (int g = 0; g < 2; ++g) {
        float mnew = fmaxf(mrun[g], pm[g]);
        float scl = fexp2(mrun[g] - mnew);
        mrun[g] = mnew;
        #pragma unroll
        for (int r = 0; r < 4; ++r) {
          float sq = u2f((unsigned)__builtin_amdgcn_ds_bpermute(
              (20 * h + r) * 4, (int)f2u(scl)));
          os[g][r] *= sq;
          #pragma unroll
          for (int dg = 0; dg < 4; ++dg) o[g][dg][r] *= sq;
        }
      }
    }

    // ---- P = exp2(S - mrun) -> bf16 pairs -> per-wave LDS [32q][64kv]
    #pragma unroll
    for (int g = 0; g < 2; ++g)
      #pragma unroll
      for (int c = 0; c < 4; ++c) {
        int w0 = cvtpk(fexp2(s[g][c][0] - mrun[g]),
                       fexp2(s[g][c][1] - mrun[g]));
        int w1 = cvtpk(fexp2(s[g][c][2] - mrun[g]),
                       fexp2(s[g][c][3] - mrun[g]));
        int* dst = (int*)(pb + g * 2048 + prow + ((c * 32 + h * 8) ^ pxor));
        dst[0] = w0; dst[1] = w1;
      }

    // ---- PV + row-sum (P A-frags re-read from LDS; same-wave, no barrier)
    __builtin_amdgcn_s_setprio(1);
    #pragma unroll
    for (int ch = 0; ch < 2; ++ch) {
      bf16x8 pa0 = *(const bf16x8*)(pb + prow +
                                    ((ch * 64 + h * 16) ^ pxor));
      bf16x8 pa1 = *(const bf16x8*)(pb + 2048 + prow +
                                    ((ch * 64 + h * 16) ^ pxor));
      os[0] = MFMA(pa0, ones, os[0]);
      os[1] = MFMA(pa1, ones, os[1]);
      #pragma unroll
      for (int dg = 0; dg < 4; ++dg) {
        bf16x8 vb = *(const bf16x8*)(smb + 8192 + ch * 4096 + dg * 1024);
        o[0][dg] = MFMA(pa0, vb, o[0][dg]);
        o[1][dg] = MFMA(pa1, vb, o[1][dg]);
      }
    }
    __builtin_amdgcn_s_setprio(0);
  }

  // ---- normalize (os[g][r] = rowsum for q = g*16+h*4+r), write AO bf16
  const int b_ = bh >> 3, head = bh & 7;
  #pragma unroll
  for (int g = 0; g < 2; ++g)
    #pragma unroll
    for (int r = 0; r < 4; ++r) {
      const float inv = 1.0f / os[g][r];
      const int row = qr0 + g * 16 + h * 4 + r;
      #pragma unroll
      for (int dg = 0; dg < 4; ++dg) {
        AO[((size_t)(b_ * 2048 + row)) * 512 + head * 64 + dg * 16 + x] =
            f2bf(o[g][dg][r] * inv);
      }
    }
}

// ---------------------------------------------------------------------------
extern "C" void kernel_launch(void* const* d_in, const int* in_sizes, int n_in,
                              void* d_out, int out_size, void* d_ws, size_t ws_size,
                              hipStream_t stream) {
  const float* x    = (const float*)d_in[0];
  const float* wqkv = (const float*)d_in[1];
  const float* wout = (const float*)d_in[2];
  const float* bout = (const float*)d_in[3];
  float* out = (float*)d_out;

  char* w = (char*)d_ws;
  u16* xh  = (u16*)(w + 0);           // 8192x512 bf16
  u16* wqh = (u16*)(w + 16777216);    // WqkvT [1536][512]
  u16* wql = (u16*)(w + 18350080);
  u16* woh = (u16*)(w + 19922944);    // WoutT [512][512]
  u16* wol = (u16*)(w + 20447232);    // (written, unused)
  u16* Qb  = (u16*)(w + 20971520);    // [32][2048][64] bf16 (pre-scaled)
  u16* Kb  = (u16*)(w + 37748736);    // [32][2048][64] bf16
  u16* Vt  = (u16*)(w + 46137344);    // [32][64][2048] bf16
  u16* AO  = (u16*)(w + 54525952);    // [8192][512] bf16; end 62914560

  k_cast  <<<4096, 256, 0, stream>>>(x, xh, 4194304);
  k_tsplit<<<3072, 256, 0, stream>>>(wqkv, wqh, wql, 1536, 786432);
  k_tsplit<<<1024, 256, 0, stream>>>(wout, woh, wol, 512, 262144);
  k_gemm_qkv<<<dim3(64, 12), 256, 0, stream>>>(xh, wqh, wql, Qb, Kb, Vt);
  k_attn<<<1024, 128, 0, stream>>>(Qb, Kb, Vt, AO);
  k_gemm_out<<<dim3(64, 4), 256, 0, stream>>>(AO, woh, bout, out);
}